// Round 1
// baseline (1076.828 us; speedup 1.0000x reference)
//
#include <hip/hip_runtime.h>
#include <math.h>

#define S_LEN 2048
#define D_DIM 1024
#define H_NUM 16
#define DK    64
#define B_NUM 2
#define M_ROWS (B_NUM * S_LEN)   // 4096

// ---------------------------------------------------------------------------
// GEMM: C[m][n] = sum_k A[m][k] * W[n][k]   (einsum 'bsd,od->bso' == A @ W^T)
// MODE 0: QKV projection. blockIdx.z selects {Wq->Q(+rope), Wk->K(+rope),
//         Wv->V}. Output written in [B][H][S][DK] layout for attention.
// MODE 1: output projection -> plain [B][S][D] (d_out).
// Tiles: 64x64 output, BK=16, 256 threads, 4x4 microtile per thread.
// LDS stored transposed As[k][m] so fragment reads are ds_read_b128.
// ---------------------------------------------------------------------------
template <int MODE>
__global__ __launch_bounds__(256)
void gemm_kernel(const float* __restrict__ A,
                 const float* __restrict__ W0,
                 const float* __restrict__ W1,
                 const float* __restrict__ W2,
                 float* __restrict__ O0,
                 float* __restrict__ O1,
                 float* __restrict__ O2,
                 const int* __restrict__ pos)
{
    const int K = D_DIM;
    const float* W;
    float* Cout;
    bool rope = false;
    if (MODE == 0) {
        const int z = blockIdx.z;
        W    = (z == 0) ? W0 : (z == 1) ? W1 : W2;
        Cout = (z == 0) ? O0 : (z == 1) ? O1 : O2;
        rope = (z < 2);
    } else {
        W = W0; Cout = O0;
    }

    // pad 68: row stride 272B (16B-aligned for float4 reads, banks spread)
    __shared__ float As[16][68];
    __shared__ float Bs[16][68];

    const int tid = threadIdx.x;
    const int tx = tid & 15;
    const int ty = tid >> 4;
    const int bm = blockIdx.y << 6;
    const int bn = blockIdx.x << 6;

    const int lr = tid >> 2;         // 0..63: row within tile
    const int lc = (tid & 3) << 2;   // 0,4,8,12: col within K-tile

    const float* Aptr = A + (size_t)(bm + lr) * K + lc;
    const float* Wptr = W + (size_t)(bn + lr) * K + lc;

    float acc[4][4] = {};

    // software prefetch of the first tile
    float4 av = *(const float4*)(Aptr);
    float4 wv = *(const float4*)(Wptr);

    for (int k0 = 0; k0 < K; k0 += 16) {
        __syncthreads();   // protect previous iteration's LDS readers
        As[lc+0][lr] = av.x; As[lc+1][lr] = av.y; As[lc+2][lr] = av.z; As[lc+3][lr] = av.w;
        Bs[lc+0][lr] = wv.x; Bs[lc+1][lr] = wv.y; Bs[lc+2][lr] = wv.z; Bs[lc+3][lr] = wv.w;
        __syncthreads();
        if (k0 + 16 < K) {           // prefetch next tile under compute
            av = *(const float4*)(Aptr + k0 + 16);
            wv = *(const float4*)(Wptr + k0 + 16);
        }
        #pragma unroll
        for (int kk = 0; kk < 16; ++kk) {
            const float4 a4 = *(const float4*)&As[kk][ty << 2];
            const float4 b4 = *(const float4*)&Bs[kk][tx << 2];
            const float aa[4] = {a4.x, a4.y, a4.z, a4.w};
            const float bb[4] = {b4.x, b4.y, b4.z, b4.w};
            #pragma unroll
            for (int i = 0; i < 4; ++i)
                #pragma unroll
                for (int j = 0; j < 4; ++j)
                    acc[i][j] = fmaf(aa[i], bb[j], acc[i][j]);
        }
    }

    #pragma unroll
    for (int i = 0; i < 4; ++i) {
        const int m = bm + (ty << 2) + i;
        if (MODE == 0) {
            const int b = m >> 11;            // m / S_LEN
            const int s = m & (S_LEN - 1);
            const float pv = (float)pos[s];
            #pragma unroll
            for (int jp = 0; jp < 2; ++jp) {
                const int n = bn + (tx << 2) + (jp << 1);
                float c0 = acc[i][jp*2+0];
                float c1 = acc[i][jp*2+1];
                if (rope) {
                    // freqs = theta^(-k/d_k), k = 2*fi, d_k = 64
                    const int fi = (n & 63) >> 1;
                    const float freq = powf(10000.0f, -(float)(2*fi) * (1.0f/64.0f));
                    const float ang = pv * freq;
                    float sn, cs;
                    sincosf(ang, &sn, &cs);
                    const float y0 = c0*cs - c1*sn;
                    const float y1 = c0*sn + c1*cs;
                    c0 = y0; c1 = y1;
                }
                const int h = n >> 6;
                const int d = n & 63;
                float* dst = Cout + (((size_t)(b * H_NUM + h) * S_LEN + s) << 6) + d;
                dst[0] = c0;
                dst[1] = c1;
            }
        } else {
            float4 val;
            val.x = acc[i][0]; val.y = acc[i][1]; val.z = acc[i][2]; val.w = acc[i][3];
            *(float4*)(Cout + (size_t)m * D_DIM + bn + (tx << 2)) = val;
        }
    }
}

// ---------------------------------------------------------------------------
// Flash-style causal attention, fp32. One block per (q-tile of 64, b*h).
// Q,K,V in [B*H][S][64]. Output in [B][S][D] layout for the final GEMM.
// In-register online softmax: row q lives in 16 consecutive lanes -> shfl_xor.
// ---------------------------------------------------------------------------
__global__ __launch_bounds__(256)
void flash_kernel(const float* __restrict__ Q,
                  const float* __restrict__ Kin,
                  const float* __restrict__ V,
                  float* __restrict__ Oout)
{
    __shared__ float Qs[64][68];   // [d][q] transposed
    __shared__ float Ks[64][68];   // [d][kv] transposed
    __shared__ float Vs[64][68];   // [kv][d] natural
    __shared__ float Ps[64][72];   // [kv][q] transposed P (pad 72: 4-way max)

    const int qt  = blockIdx.x;    // 0..31
    const int bh  = blockIdx.y;    // 0..31
    const int tid = threadIdx.x;
    const int tx  = tid & 15;
    const int ty  = tid >> 4;
    const int qbase = qt << 6;

    const float* Qp = Q   + ((size_t)bh * S_LEN + qbase) * DK;
    const float* Kp = Kin + (size_t)bh * S_LEN * DK;
    const float* Vp = V   + (size_t)bh * S_LEN * DK;

    #pragma unroll
    for (int it = 0; it < 4; ++it) {
        const int idx = tid + (it << 8);
        const int r = idx >> 4;
        const int c = (idx & 15) << 2;
        const float4 v = *(const float4*)(Qp + (r << 6) + c);
        Qs[c+0][r] = v.x; Qs[c+1][r] = v.y; Qs[c+2][r] = v.z; Qs[c+3][r] = v.w;
    }

    float o[4][4] = {};
    float mrun[4], lrun[4];
    #pragma unroll
    for (int i = 0; i < 4; ++i) { mrun[i] = -1e30f; lrun[i] = 0.0f; }

    for (int t = 0; t <= qt; ++t) {
        const int kvbase = t << 6;
        __syncthreads();   // prior iter's Ks/Vs/Ps readers done
        #pragma unroll
        for (int it = 0; it < 4; ++it) {
            const int idx = tid + (it << 8);
            const int r = idx >> 4;
            const int c = (idx & 15) << 2;
            const float4 kv = *(const float4*)(Kp + ((size_t)(kvbase + r) << 6) + c);
            Ks[c+0][r] = kv.x; Ks[c+1][r] = kv.y; Ks[c+2][r] = kv.z; Ks[c+3][r] = kv.w;
            const float4 vv = *(const float4*)(Vp + ((size_t)(kvbase + r) << 6) + c);
            *(float4*)&Vs[r][c] = vv;
        }
        __syncthreads();

        // S = Q K^T
        float sc[4][4] = {};
        #pragma unroll 8
        for (int d = 0; d < 64; ++d) {
            const float4 a4 = *(const float4*)&Qs[d][ty << 2];
            const float4 b4 = *(const float4*)&Ks[d][tx << 2];
            const float aa[4] = {a4.x, a4.y, a4.z, a4.w};
            const float bb[4] = {b4.x, b4.y, b4.z, b4.w};
            #pragma unroll
            for (int i = 0; i < 4; ++i)
                #pragma unroll
                for (int j = 0; j < 4; ++j)
                    sc[i][j] = fmaf(aa[i], bb[j], sc[i][j]);
        }

        // scale + causal mask + online softmax (16-lane row groups)
        const bool diag = (t == qt);
        #pragma unroll
        for (int i = 0; i < 4; ++i) {
            const int qrow = qbase + (ty << 2) + i;
            float vmax = -1e30f;
            #pragma unroll
            for (int j = 0; j < 4; ++j) {
                float s = sc[i][j] * 0.125f;   // 1/sqrt(64)
                if (diag && (kvbase + (tx << 2) + j > qrow)) s = -1e30f;
                sc[i][j] = s;
                vmax = fmaxf(vmax, s);
            }
            #pragma unroll
            for (int msk = 1; msk < 16; msk <<= 1)
                vmax = fmaxf(vmax, __shfl_xor(vmax, msk, 64));
            const float mnew = fmaxf(mrun[i], vmax);
            const float corr = __expf(mrun[i] - mnew);
            float rsum = 0.0f;
            #pragma unroll
            for (int j = 0; j < 4; ++j) {
                const float p = __expf(sc[i][j] - mnew);
                sc[i][j] = p;
                rsum += p;
            }
            #pragma unroll
            for (int msk = 1; msk < 16; msk <<= 1)
                rsum += __shfl_xor(rsum, msk, 64);
            lrun[i] = lrun[i] * corr + rsum;
            mrun[i] = mnew;
            #pragma unroll
            for (int j = 0; j < 4; ++j) o[i][j] *= corr;
        }

        // write P transposed [kv][q]
        #pragma unroll
        for (int j = 0; j < 4; ++j)
            #pragma unroll
            for (int i = 0; i < 4; ++i)
                Ps[(tx << 2) + j][(ty << 2) + i] = sc[i][j];
        __syncthreads();

        // O += P V
        #pragma unroll 8
        for (int kv = 0; kv < 64; ++kv) {
            const float4 p4 = *(const float4*)&Ps[kv][ty << 2];
            const float4 v4 = *(const float4*)&Vs[kv][tx << 2];
            const float pp[4] = {p4.x, p4.y, p4.z, p4.w};
            const float vq[4] = {v4.x, v4.y, v4.z, v4.w};
            #pragma unroll
            for (int i = 0; i < 4; ++i)
                #pragma unroll
                for (int j = 0; j < 4; ++j)
                    o[i][j] = fmaf(pp[i], vq[j], o[i][j]);
        }
    }

    // normalize + write [B][S][D]
    const int b = bh >> 4;
    const int h = bh & 15;
    #pragma unroll
    for (int i = 0; i < 4; ++i) {
        const float inv = 1.0f / lrun[i];
        const int s = qbase + (ty << 2) + i;
        float4 val;
        val.x = o[i][0]*inv; val.y = o[i][1]*inv; val.z = o[i][2]*inv; val.w = o[i][3]*inv;
        *(float4*)(Oout + (size_t)(b * S_LEN + s) * D_DIM + (h << 6) + (tx << 2)) = val;
    }
}

// ---------------------------------------------------------------------------
extern "C" void kernel_launch(void* const* d_in, const int* in_sizes, int n_in,
                              void* d_out, int out_size, void* d_ws, size_t ws_size,
                              hipStream_t stream)
{
    const float* x  = (const float*)d_in[0];
    const int*  pos = (const int*) d_in[1];
    const float* Wq = (const float*)d_in[2];
    const float* Wk = (const float*)d_in[3];
    const float* Wv = (const float*)d_in[4];
    const float* Wo = (const float*)d_in[5];
    float* out = (float*)d_out;

    const size_t elems = (size_t)B_NUM * S_LEN * D_DIM;  // 4,194,304 floats
    float* qws = (float*)d_ws;          // [B][H][S][DK]
    float* kws = qws + elems;
    float* vws = kws + elems;
    float* aws = vws + elems;           // [B][S][D]

    // QKV projections + RoPE (z = 0:Q, 1:K, 2:V)
    dim3 gq(D_DIM / 64, M_ROWS / 64, 3);
    gemm_kernel<0><<<gq, dim3(256), 0, stream>>>(x, Wq, Wk, Wv, qws, kws, vws, pos);

    // causal flash attention
    dim3 gf(S_LEN / 64, B_NUM * H_NUM);
    flash_kernel<<<gf, dim3(256), 0, stream>>>(qws, kws, vws, aws);

    // output projection
    dim3 go(D_DIM / 64, M_ROWS / 64, 1);
    gemm_kernel<1><<<go, dim3(256), 0, stream>>>(aws, Wo, nullptr, nullptr,
                                                 out, nullptr, nullptr, nullptr);
}

// Round 7
// 677.976 us; speedup vs baseline: 1.5883x; 1.5883x over previous
//
#include <hip/hip_runtime.h>
#include <math.h>

#define S_LEN 2048
#define D_DIM 1024
#define H_NUM 16
#define DK    64
#define B_NUM 2
#define M_ROWS (B_NUM * S_LEN)   // 4096

typedef __attribute__((ext_vector_type(8))) short sh8;   // 8 bf16 (4 VGPRs)
typedef __attribute__((ext_vector_type(4))) float f32x4; // MFMA C/D

// fp32 -> bf16 hi (RNE) + bf16 lo (residual, RNE). a - float(hi) is exact.
__device__ inline void cvt8(const float4 a, const float4 b, sh8& hi, sh8& lo)
{
    float in[8] = {a.x, a.y, a.z, a.w, b.x, b.y, b.z, b.w};
    #pragma unroll
    for (int i = 0; i < 8; ++i) {
        unsigned u  = __float_as_uint(in[i]);
        unsigned hr = (u + 0x7FFFu + ((u >> 16) & 1u)) >> 16;
        float    hf = __uint_as_float(hr << 16);
        hi[i] = (short)hr;
        float    r  = in[i] - hf;
        unsigned ur = __float_as_uint(r);
        unsigned lr = (ur + 0x7FFFu + ((ur >> 16) & 1u)) >> 16;
        lo[i] = (short)lr;
    }
}

// ---------------------------------------------------------------------------
// MFMA GEMM with bf16 hi/lo split (3 MFMA passes ~ fp32 precision).
// C[m][n] = sum_k A[m][k] * W[n][k]
// MODE 0: QKV fused (blockIdx.z -> Wq/Wk/Wv), RoPE fused for z<2,
//         output [B][H][S][DK]. MODE 1: out-projection -> [M][D].
// Tile 128x128, BK=64, 256 thr = 4 waves, wave = 64x64 (4x4 frags 16x16x32).
// LDS rows 64 bf16 (128B), 16B chunks XOR-swizzled: chunk ^= (row&7).
// ---------------------------------------------------------------------------
template <int MODE>
__global__ __launch_bounds__(256)
void gemm_mfma(const float* __restrict__ A,
               const float* __restrict__ W0,
               const float* __restrict__ W1,
               const float* __restrict__ W2,
               float* __restrict__ O0,
               float* __restrict__ O1,
               float* __restrict__ O2,
               const int* __restrict__ pos)
{
    const float* W; float* Cout; bool rope = false;
    if (MODE == 0) {
        const int z = blockIdx.z;
        W    = (z == 0) ? W0 : (z == 1) ? W1 : W2;
        Cout = (z == 0) ? O0 : (z == 1) ? O1 : O2;
        rope = (z < 2);
    } else { W = W0; Cout = O0; }

    __shared__ short Ah[128 * 64];
    __shared__ short Al[128 * 64];
    __shared__ short Bh[128 * 64];
    __shared__ short Bl[128 * 64];

    const int tid  = threadIdx.x;
    const int bm   = blockIdx.y << 7;
    const int bn   = blockIdx.x << 7;
    const int wid  = tid >> 6;
    const int lane = tid & 63;
    const int wr   = wid >> 1;          // wave sub-tile row (0..1)
    const int wc   = wid & 1;           // wave sub-tile col (0..1)
    const int l15  = lane & 15;
    const int lg   = lane >> 4;         // 0..3

    f32x4 acc[4][4];
    const f32x4 z4 = {0.f, 0.f, 0.f, 0.f};
    #pragma unroll
    for (int i = 0; i < 4; ++i)
        #pragma unroll
        for (int j = 0; j < 4; ++j) acc[i][j] = z4;

    for (int step = 0; step < 16; ++step) {
        const int k0 = step << 6;
        __syncthreads();   // prior iteration's frag readers done
        #pragma unroll
        for (int cc = 0; cc < 4; ++cc) {           // A tile: 128x64 fp32
            const int q   = tid + (cc << 8);
            const int row = q >> 3;
            const int ch  = q & 7;
            const float* src = A + (size_t)(bm + row) * D_DIM + k0 + (ch << 3);
            float4 a0 = *(const float4*)src;
            float4 a1 = *(const float4*)(src + 4);
            sh8 hv, lv; cvt8(a0, a1, hv, lv);
            const int widx = (row << 6) + ((ch ^ (row & 7)) << 3);
            *(sh8*)&Ah[widx] = hv;
            *(sh8*)&Al[widx] = lv;
        }
        #pragma unroll
        for (int cc = 0; cc < 4; ++cc) {           // B tile (weights)
            const int q   = tid + (cc << 8);
            const int row = q >> 3;
            const int ch  = q & 7;
            const float* src = W + (size_t)(bn + row) * D_DIM + k0 + (ch << 3);
            float4 a0 = *(const float4*)src;
            float4 a1 = *(const float4*)(src + 4);
            sh8 hv, lv; cvt8(a0, a1, hv, lv);
            const int widx = (row << 6) + ((ch ^ (row & 7)) << 3);
            *(sh8*)&Bh[widx] = hv;
            *(sh8*)&Bl[widx] = lv;
        }
        __syncthreads();

        #pragma unroll
        for (int kf = 0; kf < 2; ++kf) {
            sh8 fah[4], fal[4], fbh[4], fbl[4];
            #pragma unroll
            for (int fm = 0; fm < 4; ++fm) {
                const int row = (wr << 6) + (fm << 4) + l15;
                const int idx = (row << 6) + ((((kf << 2) + lg) ^ (row & 7)) << 3);
                fah[fm] = *(const sh8*)&Ah[idx];
                fal[fm] = *(const sh8*)&Al[idx];
            }
            #pragma unroll
            for (int fn = 0; fn < 4; ++fn) {
                const int row = (wc << 6) + (fn << 4) + l15;
                const int idx = (row << 6) + ((((kf << 2) + lg) ^ (row & 7)) << 3);
                fbh[fn] = *(const sh8*)&Bh[idx];
                fbl[fn] = *(const sh8*)&Bl[idx];
            }
            #pragma unroll
            for (int fm = 0; fm < 4; ++fm)
                #pragma unroll
                for (int fn = 0; fn < 4; ++fn) {
                    f32x4 c = acc[fm][fn];
                    c = __builtin_amdgcn_mfma_f32_16x16x32_bf16(fah[fm], fbh[fn], c, 0, 0, 0);
                    c = __builtin_amdgcn_mfma_f32_16x16x32_bf16(fah[fm], fbl[fn], c, 0, 0, 0);
                    c = __builtin_amdgcn_mfma_f32_16x16x32_bf16(fal[fm], fbh[fn], c, 0, 0, 0);
                    acc[fm][fn] = c;
                }
        }
    }

    // epilogue: C/D layout col = lane&15, row = (lane>>4)*4 + reg  [m89]
    #pragma unroll
    for (int fn = 0; fn < 4; ++fn) {
        const int colg = bn + (wc << 6) + (fn << 4) + l15;
        float freq = 0.f;
        if (MODE == 0 && rope) {
            const int f = (colg & 63) >> 1;
            freq = powf(10000.0f, -(float)(2 * f) * (1.0f / 64.0f));
        }
        #pragma unroll
        for (int fm = 0; fm < 4; ++fm) {
            #pragma unroll
            for (int r = 0; r < 4; ++r) {
                const int m = bm + (wr << 6) + (fm << 4) + (lg << 2) + r;
                float own = acc[fm][fn][r];
                if (MODE == 0) {
                    const int b = m >> 11, s = m & (S_LEN - 1);
                    const int h = colg >> 6, d = colg & 63;
                    float y = own;
                    float other = __shfl_xor(own, 1, 64);
                    if (rope) {
                        const float ang = (float)pos[s] * freq;
                        float sn, cs; sincosf(ang, &sn, &cs);
                        y = (d & 1) ? fmaf(other, sn, own * cs)
                                    : fmaf(-other, sn, own * cs);
                    }
                    Cout[((size_t)(b * H_NUM + h) * S_LEN + s) * DK + d] = y;
                } else {
                    Cout[(size_t)m * D_DIM + colg] = own;
                }
            }
        }
    }
}

// ---------------------------------------------------------------------------
// Flash causal attention, fp32 vector. Balanced pairs: block handles q-tiles
// {pair, 31-pair} -> uniform 33 kv-tiles/block, grid 512 = 2/CU resident.
// Ps stored NATURAL [q][kv] (float4 writes, ~2-way banks; reads broadcast).
// ---------------------------------------------------------------------------
__global__ __launch_bounds__(256)
void flash_kernel(const float* __restrict__ Q,
                  const float* __restrict__ Kin,
                  const float* __restrict__ V,
                  float* __restrict__ Oout)
{
    __shared__ float Qs[64][68];   // [d][q]
    __shared__ float Ks[64][68];   // [d][kv]
    __shared__ float Vs[64][68];   // [kv][d]
    __shared__ float Ps[64][68];   // [q][kv]  natural

    const int pair = blockIdx.x;   // 0..15
    const int bh   = blockIdx.y;   // 0..31
    const int tid  = threadIdx.x;
    const int tx   = tid & 15;
    const int ty   = tid >> 4;
    const float* Kp = Kin + (size_t)bh * S_LEN * DK;
    const float* Vp = V   + (size_t)bh * S_LEN * DK;
    const int b = bh >> 4, h = bh & 15;

    for (int half = 0; half < 2; ++half) {
        const int qt    = half ? (31 - pair) : pair;
        const int qbase = qt << 6;
        const float* Qp = Q + ((size_t)bh * S_LEN + qbase) * DK;

        #pragma unroll
        for (int it = 0; it < 4; ++it) {
            const int idx = tid + (it << 8);
            const int r = idx >> 4, c = (idx & 15) << 2;
            const float4 v4 = *(const float4*)(Qp + (r << 6) + c);
            Qs[c+0][r] = v4.x; Qs[c+1][r] = v4.y; Qs[c+2][r] = v4.z; Qs[c+3][r] = v4.w;
        }

        float o[4][4] = {};
        float mrun[4], lrun[4];
        #pragma unroll
        for (int i = 0; i < 4; ++i) { mrun[i] = -1e30f; lrun[i] = 0.0f; }

        for (int t = 0; t <= qt; ++t) {
            const int kvbase = t << 6;
            __syncthreads();
            #pragma unroll
            for (int it = 0; it < 4; ++it) {
                const int idx = tid + (it << 8);
                const int r = idx >> 4, c = (idx & 15) << 2;
                const float4 kv = *(const float4*)(Kp + ((size_t)(kvbase + r) << 6) + c);
                Ks[c+0][r] = kv.x; Ks[c+1][r] = kv.y; Ks[c+2][r] = kv.z; Ks[c+3][r] = kv.w;
                const float4 vv = *(const float4*)(Vp + ((size_t)(kvbase + r) << 6) + c);
                *(float4*)&Vs[r][c] = vv;
            }
            __syncthreads();

            float sc[4][4] = {};
            #pragma unroll 8
            for (int d = 0; d < 64; ++d) {
                const float4 a4 = *(const float4*)&Qs[d][ty << 2];
                const float4 b4 = *(const float4*)&Ks[d][tx << 2];
                const float aa[4] = {a4.x, a4.y, a4.z, a4.w};
                const float bb[4] = {b4.x, b4.y, b4.z, b4.w};
                #pragma unroll
                for (int i = 0; i < 4; ++i)
                    #pragma unroll
                    for (int j = 0; j < 4; ++j)
                        sc[i][j] = fmaf(aa[i], bb[j], sc[i][j]);
            }

            const bool diag = (t == qt);
            #pragma unroll
            for (int i = 0; i < 4; ++i) {
                const int qrow = qbase + (ty << 2) + i;
                float vmax = -1e30f;
                #pragma unroll
                for (int j = 0; j < 4; ++j) {
                    float s = sc[i][j] * 0.125f;
                    if (diag && (kvbase + (tx << 2) + j > qrow)) s = -1e30f;
                    sc[i][j] = s;
                    vmax = fmaxf(vmax, s);
                }
                #pragma unroll
                for (int msk = 1; msk < 16; msk <<= 1)
                    vmax = fmaxf(vmax, __shfl_xor(vmax, msk, 64));
                const float mnew = fmaxf(mrun[i], vmax);
                const float corr = __expf(mrun[i] - mnew);
                float rsum = 0.0f;
                #pragma unroll
                for (int j = 0; j < 4; ++j) {
                    const float p = __expf(sc[i][j] - mnew);
                    sc[i][j] = p;
                    rsum += p;
                }
                #pragma unroll
                for (int msk = 1; msk < 16; msk <<= 1)
                    rsum += __shfl_xor(rsum, msk, 64);
                lrun[i] = lrun[i] * corr + rsum;
                mrun[i] = mnew;
                #pragma unroll
                for (int j = 0; j < 4; ++j) o[i][j] *= corr;
            }

            #pragma unroll
            for (int i = 0; i < 4; ++i) {
                float4 w4;
                w4.x = sc[i][0]; w4.y = sc[i][1]; w4.z = sc[i][2]; w4.w = sc[i][3];
                *(float4*)&Ps[(ty << 2) + i][tx << 2] = w4;
            }
            __syncthreads();

            #pragma unroll 4
            for (int c0 = 0; c0 < 16; ++c0) {
                float p[4][4], vv[4][4];
                #pragma unroll
                for (int i = 0; i < 4; ++i) {
                    const float4 t4 = *(const float4*)&Ps[(ty << 2) + i][c0 << 2];
                    p[i][0] = t4.x; p[i][1] = t4.y; p[i][2] = t4.z; p[i][3] = t4.w;
                }
                #pragma unroll
                for (int c = 0; c < 4; ++c) {
                    const float4 t4 = *(const float4*)&Vs[(c0 << 2) + c][tx << 2];
                    vv[c][0] = t4.x; vv[c][1] = t4.y; vv[c][2] = t4.z; vv[c][3] = t4.w;
                }
                #pragma unroll
                for (int i = 0; i < 4; ++i)
                    #pragma unroll
                    for (int c = 0; c < 4; ++c)
                        #pragma unroll
                        for (int j = 0; j < 4; ++j)
                            o[i][j] = fmaf(p[i][c], vv[c][j], o[i][j]);
            }
        }

        #pragma unroll
        for (int i = 0; i < 4; ++i) {
            const float inv = 1.0f / lrun[i];
            const int s = qbase + (ty << 2) + i;
            float4 val;
            val.x = o[i][0]*inv; val.y = o[i][1]*inv;
            val.z = o[i][2]*inv; val.w = o[i][3]*inv;
            *(float4*)(Oout + (size_t)(b * S_LEN + s) * D_DIM + (h << 6) + (tx << 2)) = val;
        }
    }
}

// ---------------------------------------------------------------------------
extern "C" void kernel_launch(void* const* d_in, const int* in_sizes, int n_in,
                              void* d_out, int out_size, void* d_ws, size_t ws_size,
                              hipStream_t stream)
{
    const float* x  = (const float*)d_in[0];
    const int*  pos = (const int*) d_in[1];
    const float* Wq = (const float*)d_in[2];
    const float* Wk = (const float*)d_in[3];
    const float* Wv = (const float*)d_in[4];
    const float* Wo = (const float*)d_in[5];
    float* out = (float*)d_out;

    const size_t elems = (size_t)B_NUM * S_LEN * D_DIM;
    float* qws = (float*)d_ws;          // [B][H][S][DK]
    float* kws = qws + elems;
    float* vws = kws + elems;
    float* aws = vws + elems;           // [B][S][D]

    dim3 gq(D_DIM / 128, M_ROWS / 128, 3);
    gemm_mfma<0><<<gq, dim3(256), 0, stream>>>(x, Wq, Wk, Wv, qws, kws, vws, pos);

    dim3 gf(16, B_NUM * H_NUM);
    flash_kernel<<<gf, dim3(256), 0, stream>>>(qws, kws, vws, aws);

    dim3 go(D_DIM / 128, M_ROWS / 128, 1);
    gemm_mfma<1><<<go, dim3(256), 0, stream>>>(aws, Wo, nullptr, nullptr,
                                               out, nullptr, nullptr, nullptr);
}

// Round 8
// 503.899 us; speedup vs baseline: 2.1370x; 1.3455x over previous
//
#include <hip/hip_runtime.h>
#include <math.h>

#define S_LEN 2048
#define D_DIM 1024
#define H_NUM 16
#define DK    64
#define B_NUM 2
#define M_ROWS (B_NUM * S_LEN)   // 4096

typedef __attribute__((ext_vector_type(8))) short sh8;   // 8 bf16 (4 VGPRs)
typedef __attribute__((ext_vector_type(4))) float f32x4; // MFMA C/D

// fp32 -> bf16 hi (RNE) + bf16 lo (residual, RNE). a - float(hi) is exact.
__device__ inline void cvt8(const float4 a, const float4 b, sh8& hi, sh8& lo)
{
    float in[8] = {a.x, a.y, a.z, a.w, b.x, b.y, b.z, b.w};
    #pragma unroll
    for (int i = 0; i < 8; ++i) {
        unsigned u  = __float_as_uint(in[i]);
        unsigned hr = (u + 0x7FFFu + ((u >> 16) & 1u)) >> 16;
        float    hf = __uint_as_float(hr << 16);
        hi[i] = (short)hr;
        float    r  = in[i] - hf;
        unsigned ur = __float_as_uint(r);
        unsigned lr = (ur + 0x7FFFu + ((ur >> 16) & 1u)) >> 16;
        lo[i] = (short)lr;
    }
}

__device__ inline void cvt1(float x, short& h, short& l)
{
    unsigned u  = __float_as_uint(x);
    unsigned hr = (u + 0x7FFFu + ((u >> 16) & 1u)) >> 16;
    h = (short)hr;
    float    r  = x - __uint_as_float(hr << 16);
    unsigned ur = __float_as_uint(r);
    l = (short)((ur + 0x7FFFu + ((ur >> 16) & 1u)) >> 16);
}

// ---------------------------------------------------------------------------
// MFMA GEMM with bf16 hi/lo split (3 MFMA passes ~ fp32 precision).
// VERIFIED R7: passed, absmax 0.0078125. Unchanged this round.
// ---------------------------------------------------------------------------
template <int MODE>
__global__ __launch_bounds__(256)
void gemm_mfma(const float* __restrict__ A,
               const float* __restrict__ W0,
               const float* __restrict__ W1,
               const float* __restrict__ W2,
               float* __restrict__ O0,
               float* __restrict__ O1,
               float* __restrict__ O2,
               const int* __restrict__ pos)
{
    const float* W; float* Cout; bool rope = false;
    if (MODE == 0) {
        const int z = blockIdx.z;
        W    = (z == 0) ? W0 : (z == 1) ? W1 : W2;
        Cout = (z == 0) ? O0 : (z == 1) ? O1 : O2;
        rope = (z < 2);
    } else { W = W0; Cout = O0; }

    __shared__ short Ah[128 * 64];
    __shared__ short Al[128 * 64];
    __shared__ short Bh[128 * 64];
    __shared__ short Bl[128 * 64];

    const int tid  = threadIdx.x;
    const int bm   = blockIdx.y << 7;
    const int bn   = blockIdx.x << 7;
    const int wid  = tid >> 6;
    const int lane = tid & 63;
    const int wr   = wid >> 1;
    const int wc   = wid & 1;
    const int l15  = lane & 15;
    const int lg   = lane >> 4;

    f32x4 acc[4][4];
    const f32x4 z4 = {0.f, 0.f, 0.f, 0.f};
    #pragma unroll
    for (int i = 0; i < 4; ++i)
        #pragma unroll
        for (int j = 0; j < 4; ++j) acc[i][j] = z4;

    for (int step = 0; step < 16; ++step) {
        const int k0 = step << 6;
        __syncthreads();
        #pragma unroll
        for (int cc = 0; cc < 4; ++cc) {
            const int q   = tid + (cc << 8);
            const int row = q >> 3;
            const int ch  = q & 7;
            const float* src = A + (size_t)(bm + row) * D_DIM + k0 + (ch << 3);
            float4 a0 = *(const float4*)src;
            float4 a1 = *(const float4*)(src + 4);
            sh8 hv, lv; cvt8(a0, a1, hv, lv);
            const int widx = (row << 6) + ((ch ^ (row & 7)) << 3);
            *(sh8*)&Ah[widx] = hv;
            *(sh8*)&Al[widx] = lv;
        }
        #pragma unroll
        for (int cc = 0; cc < 4; ++cc) {
            const int q   = tid + (cc << 8);
            const int row = q >> 3;
            const int ch  = q & 7;
            const float* src = W + (size_t)(bn + row) * D_DIM + k0 + (ch << 3);
            float4 a0 = *(const float4*)src;
            float4 a1 = *(const float4*)(src + 4);
            sh8 hv, lv; cvt8(a0, a1, hv, lv);
            const int widx = (row << 6) + ((ch ^ (row & 7)) << 3);
            *(sh8*)&Bh[widx] = hv;
            *(sh8*)&Bl[widx] = lv;
        }
        __syncthreads();

        #pragma unroll
        for (int kf = 0; kf < 2; ++kf) {
            sh8 fah[4], fal[4], fbh[4], fbl[4];
            #pragma unroll
            for (int fm = 0; fm < 4; ++fm) {
                const int row = (wr << 6) + (fm << 4) + l15;
                const int idx = (row << 6) + ((((kf << 2) + lg) ^ (row & 7)) << 3);
                fah[fm] = *(const sh8*)&Ah[idx];
                fal[fm] = *(const sh8*)&Al[idx];
            }
            #pragma unroll
            for (int fn = 0; fn < 4; ++fn) {
                const int row = (wc << 6) + (fn << 4) + l15;
                const int idx = (row << 6) + ((((kf << 2) + lg) ^ (row & 7)) << 3);
                fbh[fn] = *(const sh8*)&Bh[idx];
                fbl[fn] = *(const sh8*)&Bl[idx];
            }
            #pragma unroll
            for (int fm = 0; fm < 4; ++fm)
                #pragma unroll
                for (int fn = 0; fn < 4; ++fn) {
                    f32x4 c = acc[fm][fn];
                    c = __builtin_amdgcn_mfma_f32_16x16x32_bf16(fah[fm], fbh[fn], c, 0, 0, 0);
                    c = __builtin_amdgcn_mfma_f32_16x16x32_bf16(fah[fm], fbl[fn], c, 0, 0, 0);
                    c = __builtin_amdgcn_mfma_f32_16x16x32_bf16(fal[fm], fbh[fn], c, 0, 0, 0);
                    acc[fm][fn] = c;
                }
        }
    }

    #pragma unroll
    for (int fn = 0; fn < 4; ++fn) {
        const int colg = bn + (wc << 6) + (fn << 4) + l15;
        float freq = 0.f;
        if (MODE == 0 && rope) {
            const int f = (colg & 63) >> 1;
            freq = powf(10000.0f, -(float)(2 * f) * (1.0f / 64.0f));
        }
        #pragma unroll
        for (int fm = 0; fm < 4; ++fm) {
            #pragma unroll
            for (int r = 0; r < 4; ++r) {
                const int m = bm + (wr << 6) + (fm << 4) + (lg << 2) + r;
                float own = acc[fm][fn][r];
                if (MODE == 0) {
                    const int b = m >> 11, s = m & (S_LEN - 1);
                    const int h = colg >> 6, d = colg & 63;
                    float y = own;
                    float other = __shfl_xor(own, 1, 64);
                    if (rope) {
                        const float ang = (float)pos[s] * freq;
                        float sn, cs; sincosf(ang, &sn, &cs);
                        y = (d & 1) ? fmaf(other, sn, own * cs)
                                    : fmaf(-other, sn, own * cs);
                    }
                    Cout[((size_t)(b * H_NUM + h) * S_LEN + s) * DK + d] = y;
                } else {
                    Cout[(size_t)m * D_DIM + colg] = own;
                }
            }
        }
    }
}

// ---------------------------------------------------------------------------
// Flash causal attention — MFMA version (hi/lo bf16, 3-MFMA per pair).
// 4 waves/block; wave w owns q-rows [16w,16w+16) of the 64-row q-tile.
// Balanced pairs {pair, 31-pair} retained. LDS: Q/K natural [row][d] bf16
// (16B chunks swizzled chunk^=(row&7), conflict-free sh8 staging);
// V transposed to [d][kv] (scalar bf16 writes spread over 32 banks);
// P acc->LDS per-wave stripe (no barrier needed), read back as A-frags.
// ---------------------------------------------------------------------------
__global__ __launch_bounds__(256)
void flash_kernel(const float* __restrict__ Q,
                  const float* __restrict__ Kin,
                  const float* __restrict__ V,
                  float* __restrict__ Oout)
{
    __shared__ short Qh[4096], Ql[4096];
    __shared__ short Kh[4096], Kl[4096];
    __shared__ short Vh[4096], Vl[4096];   // transposed [d][kv]
    __shared__ short Ph[4096], Pl[4096];   // [q][kv]

    const int pair = blockIdx.x;   // 0..15
    const int bh   = blockIdx.y;   // 0..31
    const int tid  = threadIdx.x;
    const int lane = tid & 63;
    const int w    = tid >> 6;     // wave 0..3
    const int l15  = lane & 15;
    const int lg   = lane >> 4;    // 0..3

    const float* Kp = Kin + (size_t)bh * S_LEN * DK;
    const float* Vp = V   + (size_t)bh * S_LEN * DK;
    const int b = bh >> 4, h = bh & 15;

    const int srow = tid >> 2;          // Q/K staging row 0..63
    const int sc4  = tid & 3;
    const int vr   = tid & 63;          // V staging: kv row
    const int vd0  = (tid >> 6) << 4;   // V staging: d block (16 per wave)

    for (int half = 0; half < 2; ++half) {
        const int qt    = half ? (31 - pair) : pair;
        const int qbase = qt << 6;

        __syncthreads();   // protect Qh/Ql from prior half's frag readers
        {   // stage Q (natural [q][d], swizzled chunks)
            const float* qsrc = Q + ((size_t)bh * S_LEN + qbase + srow) * DK;
            #pragma unroll
            for (int s = 0; s < 2; ++s) {
                const int ch = sc4 + (s << 2);
                const float4 a0 = *(const float4*)(qsrc + (ch << 3));
                const float4 a1 = *(const float4*)(qsrc + (ch << 3) + 4);
                sh8 hv, lv; cvt8(a0, a1, hv, lv);
                const int idx = (srow << 6) + ((ch ^ (srow & 7)) << 3);
                *(sh8*)&Qh[idx] = hv; *(sh8*)&Ql[idx] = lv;
            }
        }

        f32x4 oacc[4];
        const f32x4 z4 = {0.f, 0.f, 0.f, 0.f};
        float mrun[4], lrun[4];
        #pragma unroll
        for (int i = 0; i < 4; ++i) { oacc[i] = z4; mrun[i] = -1e30f; lrun[i] = 0.f; }

        for (int t = 0; t <= qt; ++t) {
            const int kvbase = t << 6;
            __syncthreads();   // prior tile's K/V frag readers done
            {   // stage K (natural [kv][d])
                const float* ksrc = Kp + (size_t)(kvbase + srow) * DK;
                #pragma unroll
                for (int s = 0; s < 2; ++s) {
                    const int ch = sc4 + (s << 2);
                    const float4 a0 = *(const float4*)(ksrc + (ch << 3));
                    const float4 a1 = *(const float4*)(ksrc + (ch << 3) + 4);
                    sh8 hv, lv; cvt8(a0, a1, hv, lv);
                    const int idx = (srow << 6) + ((ch ^ (srow & 7)) << 3);
                    *(sh8*)&Kh[idx] = hv; *(sh8*)&Kl[idx] = lv;
                }
            }
            {   // stage V transposed -> [d][kv]
                const float* vsrc = Vp + (size_t)(kvbase + vr) * DK + vd0;
                const float4 v0 = *(const float4*)(vsrc);
                const float4 v1 = *(const float4*)(vsrc + 4);
                const float4 v2 = *(const float4*)(vsrc + 8);
                const float4 v3 = *(const float4*)(vsrc + 12);
                sh8 h0, l0, h1, l1;
                cvt8(v0, v1, h0, l0);
                cvt8(v2, v3, h1, l1);
                #pragma unroll
                for (int e = 0; e < 8; ++e) {
                    int d   = vd0 + e;
                    int idx = (d << 6) + ((((vr >> 3)) ^ (d & 7)) << 3) + (vr & 7);
                    Vh[idx] = h0[e]; Vl[idx] = l0[e];
                    d   = vd0 + 8 + e;
                    idx = (d << 6) + ((((vr >> 3)) ^ (d & 7)) << 3) + (vr & 7);
                    Vh[idx] = h1[e]; Vl[idx] = l1[e];
                }
            }
            __syncthreads();

            // ---- QK^T : D[q][kv], A=Q[m=q][k=d], B=K[n=kv][k=d]
            f32x4 sacc[4];
            #pragma unroll
            for (int fn = 0; fn < 4; ++fn) sacc[fn] = z4;
            #pragma unroll
            for (int kf = 0; kf < 2; ++kf) {
                const int arow = (w << 4) + l15;
                const int aidx = (arow << 6) + ((((kf << 2) + lg) ^ (arow & 7)) << 3);
                const sh8 qh = *(const sh8*)&Qh[aidx];
                const sh8 ql = *(const sh8*)&Ql[aidx];
                #pragma unroll
                for (int fn = 0; fn < 4; ++fn) {
                    const int brow = (fn << 4) + l15;
                    const int bidx = (brow << 6) + ((((kf << 2) + lg) ^ (brow & 7)) << 3);
                    const sh8 kh = *(const sh8*)&Kh[bidx];
                    const sh8 kl = *(const sh8*)&Kl[bidx];
                    f32x4 c = sacc[fn];
                    c = __builtin_amdgcn_mfma_f32_16x16x32_bf16(qh, kh, c, 0, 0, 0);
                    c = __builtin_amdgcn_mfma_f32_16x16x32_bf16(qh, kl, c, 0, 0, 0);
                    c = __builtin_amdgcn_mfma_f32_16x16x32_bf16(ql, kh, c, 0, 0, 0);
                    sacc[fn] = c;
                }
            }

            // ---- online softmax on acc layout: row q=(lg<<2)+reg, col kv=16fn+l15
            const bool diag = (t == qt);
            #pragma unroll
            for (int reg = 0; reg < 4; ++reg) {
                const int qg = qbase + (w << 4) + (lg << 2) + reg;
                float sv[4];
                float vmax = -1e30f;
                #pragma unroll
                for (int fn = 0; fn < 4; ++fn) {
                    float s = sacc[fn][reg] * 0.125f;   // 1/sqrt(64)
                    if (diag && (kvbase + (fn << 4) + l15 > qg)) s = -1e30f;
                    sv[fn] = s;
                    vmax = fmaxf(vmax, s);
                }
                #pragma unroll
                for (int msk = 1; msk < 16; msk <<= 1)
                    vmax = fmaxf(vmax, __shfl_xor(vmax, msk, 64));
                const float mnew = fmaxf(mrun[reg], vmax);
                const float corr = __expf(mrun[reg] - mnew);
                float rsum = 0.f;
                const int prow = (w << 4) + (lg << 2) + reg;
                #pragma unroll
                for (int fn = 0; fn < 4; ++fn) {
                    const float p = __expf(sv[fn] - mnew);
                    rsum += p;
                    short hs, ls; cvt1(p, hs, ls);
                    const int pcol = (fn << 4) + l15;
                    const int pidx = (prow << 6) + ((((pcol >> 3)) ^ (prow & 7)) << 3) + (pcol & 7);
                    Ph[pidx] = hs; Pl[pidx] = ls;
                }
                #pragma unroll
                for (int msk = 1; msk < 16; msk <<= 1)
                    rsum += __shfl_xor(rsum, msk, 64);
                lrun[reg] = lrun[reg] * corr + rsum;
                mrun[reg] = mnew;
                #pragma unroll
                for (int fn = 0; fn < 4; ++fn) oacc[fn][reg] *= corr;
            }

            // ---- PV : D[q][d] += P[m=q][k=kv] * Vt[n=d][k=kv]
            // P written/read by same wave only (rows [16w,16w+16)) -> no barrier
            #pragma unroll
            for (int kf = 0; kf < 2; ++kf) {
                const int arow = (w << 4) + l15;
                const int aidx = (arow << 6) + ((((kf << 2) + lg) ^ (arow & 7)) << 3);
                const sh8 ph = *(const sh8*)&Ph[aidx];
                const sh8 pl = *(const sh8*)&Pl[aidx];
                #pragma unroll
                for (int fn = 0; fn < 4; ++fn) {
                    const int brow = (fn << 4) + l15;
                    const int bidx = (brow << 6) + ((((kf << 2) + lg) ^ (brow & 7)) << 3);
                    const sh8 vh = *(const sh8*)&Vh[bidx];
                    const sh8 vl = *(const sh8*)&Vl[bidx];
                    f32x4 c = oacc[fn];
                    c = __builtin_amdgcn_mfma_f32_16x16x32_bf16(ph, vh, c, 0, 0, 0);
                    c = __builtin_amdgcn_mfma_f32_16x16x32_bf16(ph, vl, c, 0, 0, 0);
                    c = __builtin_amdgcn_mfma_f32_16x16x32_bf16(pl, vh, c, 0, 0, 0);
                    oacc[fn] = c;
                }
            }
        }

        // ---- epilogue: normalize + write [B][S][D]
        #pragma unroll
        for (int reg = 0; reg < 4; ++reg) {
            const float inv = 1.0f / lrun[reg];
            const int s = qbase + (w << 4) + (lg << 2) + reg;
            float* orow = Oout + (size_t)(b * S_LEN + s) * D_DIM + (h << 6);
            #pragma unroll
            for (int fn = 0; fn < 4; ++fn)
                orow[(fn << 4) + l15] = oacc[fn][reg] * inv;
        }
    }
}

// ---------------------------------------------------------------------------
extern "C" void kernel_launch(void* const* d_in, const int* in_sizes, int n_in,
                              void* d_out, int out_size, void* d_ws, size_t ws_size,
                              hipStream_t stream)
{
    const float* x  = (const float*)d_in[0];
    const int*  pos = (const int*) d_in[1];
    const float* Wq = (const float*)d_in[2];
    const float* Wk = (const float*)d_in[3];
    const float* Wv = (const float*)d_in[4];
    const float* Wo = (const float*)d_in[5];
    float* out = (float*)d_out;

    const size_t elems = (size_t)B_NUM * S_LEN * D_DIM;
    float* qws = (float*)d_ws;          // [B][H][S][DK]
    float* kws = qws + elems;
    float* vws = kws + elems;
    float* aws = vws + elems;           // [B][S][D]

    dim3 gq(D_DIM / 128, M_ROWS / 128, 3);
    gemm_mfma<0><<<gq, dim3(256), 0, stream>>>(x, Wq, Wk, Wv, qws, kws, vws, pos);

    dim3 gf(16, B_NUM * H_NUM);
    flash_kernel<<<gf, dim3(256), 0, stream>>>(qws, kws, vws, aws);

    dim3 go(D_DIM / 128, M_ROWS / 128, 1);
    gemm_mfma<1><<<go, dim3(256), 0, stream>>>(aws, Wo, nullptr, nullptr,
                                               out, nullptr, nullptr, nullptr);
}

// Round 9
// 400.622 us; speedup vs baseline: 2.6879x; 1.2578x over previous
//
#include <hip/hip_runtime.h>
#include <math.h>

#define S_LEN 2048
#define D_DIM 1024
#define H_NUM 16
#define DK    64
#define B_NUM 2
#define M_ROWS (B_NUM * S_LEN)   // 4096

typedef __attribute__((ext_vector_type(8))) short sh8;   // 8 bf16 (4 VGPRs)
typedef __attribute__((ext_vector_type(4))) float f32x4; // MFMA C/D

// fp32 -> bf16 hi (RNE) + bf16 lo (residual, RNE). a - float(hi) is exact.
__device__ inline void cvt8(const float4 a, const float4 b, sh8& hi, sh8& lo)
{
    float in[8] = {a.x, a.y, a.z, a.w, b.x, b.y, b.z, b.w};
    #pragma unroll
    for (int i = 0; i < 8; ++i) {
        unsigned u  = __float_as_uint(in[i]);
        unsigned hr = (u + 0x7FFFu + ((u >> 16) & 1u)) >> 16;
        float    hf = __uint_as_float(hr << 16);
        hi[i] = (short)hr;
        float    r  = in[i] - hf;
        unsigned ur = __float_as_uint(r);
        unsigned lr = (ur + 0x7FFFu + ((ur >> 16) & 1u)) >> 16;
        lo[i] = (short)lr;
    }
}

__device__ inline void cvt1(float x, short& h, short& l)
{
    unsigned u  = __float_as_uint(x);
    unsigned hr = (u + 0x7FFFu + ((u >> 16) & 1u)) >> 16;
    h = (short)hr;
    float    r  = x - __uint_as_float(hr << 16);
    unsigned ur = __float_as_uint(r);
    l = (short)((ur + 0x7FFFu + ((ur >> 16) & 1u)) >> 16);
}

#define PLANE (4u * 1024u * 1024u)   // 4M elements (one [4096][1024] plane)
#define WPLANE (1024u * 1024u)

// ===========================================================================
// split_kernel: x + 4 weights -> bf16 hi/lo planes (one-time pass).
// grid (512, 5): y=0 -> x (4 units/thread), y=1..4 -> Wq/Wk/Wv/Wo (1 unit).
// ===========================================================================
__global__ __launch_bounds__(256)
void split_kernel(const float* __restrict__ x,
                  const float* __restrict__ wq, const float* __restrict__ wk,
                  const float* __restrict__ wv, const float* __restrict__ wo,
                  short* __restrict__ xh, short* __restrict__ xl,
                  short* __restrict__ w8)
{
    const int t = blockIdx.x * 256 + threadIdx.x;   // 0..131071
    const int y = blockIdx.y;
    if (y == 0) {
        #pragma unroll
        for (int i = 0; i < 4; ++i) {
            const size_t u = (size_t)t + (size_t)i * 131072u;
            const float4 a0 = *(const float4*)(x + u * 8);
            const float4 a1 = *(const float4*)(x + u * 8 + 4);
            sh8 hv, lv; cvt8(a0, a1, hv, lv);
            *(sh8*)&xh[u * 8] = hv;
            *(sh8*)&xl[u * 8] = lv;
        }
    } else {
        const float* src = (y == 1) ? wq : (y == 2) ? wk : (y == 3) ? wv : wo;
        short* dh = w8 + (size_t)(y - 1) * 2 * WPLANE;
        short* dl = dh + WPLANE;
        const size_t u = (size_t)t;
        const float4 a0 = *(const float4*)(src + u * 8);
        const float4 a1 = *(const float4*)(src + u * 8 + 4);
        sh8 hv, lv; cvt8(a0, a1, hv, lv);
        *(sh8*)&dh[u * 8] = hv;
        *(sh8*)&dl[u * 8] = lv;
    }
}

// ===========================================================================
// gemm2: MFMA GEMM reading PRE-SPLIT bf16 hi/lo planes (no cvt in K-loop).
// C[m][n] = sum_k A[m][k] * W[n][k].  Tile 128x128, BK=64, 4 waves.
// MODE 0: A=x planes, W=w8[z], RoPE for z<2, out -> Q/K/V hi/lo planes.
// MODE 1: A=attn-out planes, W=Wo, out -> fp32 d_out.
// LDS 16B chunks XOR-swizzled chunk^=(row&7) both sides (rule #21).
// ===========================================================================
template <int MODE>
__global__ __launch_bounds__(256)
void gemm2(const short* __restrict__ Agh, const short* __restrict__ Agl,
           const short* __restrict__ w8,
           short* __restrict__ qkv,      // MODE 0 out planes base
           float* __restrict__ outf,     // MODE 1 out
           const int* __restrict__ pos)
{
    const int z = (MODE == 0) ? blockIdx.z : 3;
    const short* Wh_g = w8 + (size_t)z * 2 * WPLANE;
    const short* Wl_g = Wh_g + WPLANE;
    const bool rope = (MODE == 0) && (z < 2);
    short* Oh = (MODE == 0) ? qkv + (size_t)z * 2 * PLANE : nullptr;
    short* Ol = (MODE == 0) ? Oh + PLANE : nullptr;

    __shared__ short Ah[128 * 64];
    __shared__ short Al[128 * 64];
    __shared__ short Bh[128 * 64];
    __shared__ short Bl[128 * 64];

    const int tid  = threadIdx.x;
    const int bm   = blockIdx.y << 7;
    const int bn   = blockIdx.x << 7;
    const int wid  = tid >> 6;
    const int lane = tid & 63;
    const int wr   = wid >> 1;
    const int wc   = wid & 1;
    const int l15  = lane & 15;
    const int lg   = lane >> 4;

    f32x4 acc[4][4];
    const f32x4 z4 = {0.f, 0.f, 0.f, 0.f};
    #pragma unroll
    for (int i = 0; i < 4; ++i)
        #pragma unroll
        for (int j = 0; j < 4; ++j) acc[i][j] = z4;

    for (int step = 0; step < 16; ++step) {
        const int k0 = step << 6;
        __syncthreads();
        #pragma unroll
        for (int cc = 0; cc < 4; ++cc) {
            const int q   = tid + (cc << 8);
            const int row = q >> 3;
            const int ch  = q & 7;
            const size_t g = (size_t)(bm + row) * D_DIM + k0 + (ch << 3);
            const sh8 hv = *(const sh8*)&Agh[g];
            const sh8 lv = *(const sh8*)&Agl[g];
            const int idx = (row << 6) + ((ch ^ (row & 7)) << 3);
            *(sh8*)&Ah[idx] = hv;
            *(sh8*)&Al[idx] = lv;
        }
        #pragma unroll
        for (int cc = 0; cc < 4; ++cc) {
            const int q   = tid + (cc << 8);
            const int row = q >> 3;
            const int ch  = q & 7;
            const size_t g = (size_t)(bn + row) * D_DIM + k0 + (ch << 3);
            const sh8 hv = *(const sh8*)&Wh_g[g];
            const sh8 lv = *(const sh8*)&Wl_g[g];
            const int idx = (row << 6) + ((ch ^ (row & 7)) << 3);
            *(sh8*)&Bh[idx] = hv;
            *(sh8*)&Bl[idx] = lv;
        }
        __syncthreads();

        #pragma unroll
        for (int kf = 0; kf < 2; ++kf) {
            sh8 fah[4], fal[4], fbh[4], fbl[4];
            #pragma unroll
            for (int fm = 0; fm < 4; ++fm) {
                const int row = (wr << 6) + (fm << 4) + l15;
                const int idx = (row << 6) + ((((kf << 2) + lg) ^ (row & 7)) << 3);
                fah[fm] = *(const sh8*)&Ah[idx];
                fal[fm] = *(const sh8*)&Al[idx];
            }
            #pragma unroll
            for (int fn = 0; fn < 4; ++fn) {
                const int row = (wc << 6) + (fn << 4) + l15;
                const int idx = (row << 6) + ((((kf << 2) + lg) ^ (row & 7)) << 3);
                fbh[fn] = *(const sh8*)&Bh[idx];
                fbl[fn] = *(const sh8*)&Bl[idx];
            }
            #pragma unroll
            for (int fm = 0; fm < 4; ++fm)
                #pragma unroll
                for (int fn = 0; fn < 4; ++fn) {
                    f32x4 c = acc[fm][fn];
                    c = __builtin_amdgcn_mfma_f32_16x16x32_bf16(fah[fm], fbh[fn], c, 0, 0, 0);
                    c = __builtin_amdgcn_mfma_f32_16x16x32_bf16(fah[fm], fbl[fn], c, 0, 0, 0);
                    c = __builtin_amdgcn_mfma_f32_16x16x32_bf16(fal[fm], fbh[fn], c, 0, 0, 0);
                    acc[fm][fn] = c;
                }
        }
    }

    // epilogue: C/D layout col = lane&15, row = (lane>>4)*4 + reg  [m89]
    #pragma unroll
    for (int fn = 0; fn < 4; ++fn) {
        const int colg = bn + (wc << 6) + (fn << 4) + l15;
        float freq = 0.f;
        if (rope) {
            const int f = (colg & 63) >> 1;
            freq = powf(10000.0f, -(float)(2 * f) * (1.0f / 64.0f));
        }
        #pragma unroll
        for (int fm = 0; fm < 4; ++fm) {
            #pragma unroll
            for (int r = 0; r < 4; ++r) {
                const int m = bm + (wr << 6) + (fm << 4) + (lg << 2) + r;
                float own = acc[fm][fn][r];
                if (MODE == 0) {
                    const int b = m >> 11, s = m & (S_LEN - 1);
                    const int h = colg >> 6, d = colg & 63;
                    float y = own;
                    float other = __shfl_xor(own, 1, 64);
                    if (rope) {
                        const float ang = (float)pos[s] * freq;
                        float sn, cs; sincosf(ang, &sn, &cs);
                        y = (d & 1) ? fmaf(other, sn, own * cs)
                                    : fmaf(-other, sn, own * cs);
                    }
                    short hs, ls; cvt1(y, hs, ls);
                    const size_t addr = ((size_t)(b * H_NUM + h) * S_LEN + s) * DK + d;
                    Oh[addr] = hs; Ol[addr] = ls;
                } else {
                    outf[(size_t)m * D_DIM + colg] = own;
                }
            }
        }
    }
}

// ===========================================================================
// flash2: MFMA flash attention reading Q/K/V hi/lo planes, writing attn-out
// hi/lo planes. Core (softmax, P, MFMA, no-barrier P stripe) verbatim R8.
// ===========================================================================
__global__ __launch_bounds__(256)
void flash2(const short* __restrict__ qkv,
            short* __restrict__ ah, short* __restrict__ al)
{
    const short* Qh_g = qkv;
    const short* Ql_g = qkv + PLANE;
    const short* Kh_g = qkv + 2u * PLANE;
    const short* Kl_g = qkv + 3u * PLANE;
    const short* Vh_g = qkv + 4u * PLANE;
    const short* Vl_g = qkv + 5u * PLANE;

    __shared__ short Qh[4096], Ql[4096];
    __shared__ short Kh[4096], Kl[4096];
    __shared__ short Vh[4096], Vl[4096];   // transposed [d][kv]
    __shared__ short Ph[4096], Pl[4096];   // [q][kv]

    const int pair = blockIdx.x;   // 0..15
    const int bh   = blockIdx.y;   // 0..31
    const int tid  = threadIdx.x;
    const int lane = tid & 63;
    const int w    = tid >> 6;
    const int l15  = lane & 15;
    const int lg   = lane >> 4;

    const int b = bh >> 4, h = bh & 15;

    const int srow = tid >> 2;          // staging row 0..63
    const int sc4  = tid & 3;
    const int vr   = tid & 63;          // V staging: kv row
    const int vd0  = (tid >> 6) << 4;   // V staging: d block

    for (int half = 0; half < 2; ++half) {
        const int qt    = half ? (31 - pair) : pair;
        const int qbase = qt << 6;

        __syncthreads();   // protect Qh/Ql from prior half's readers
        {   // stage Q
            const size_t gr = ((size_t)bh * S_LEN + qbase + srow) * DK;
            #pragma unroll
            for (int s = 0; s < 2; ++s) {
                const int ch = sc4 + (s << 2);
                const sh8 hv = *(const sh8*)&Qh_g[gr + (ch << 3)];
                const sh8 lv = *(const sh8*)&Ql_g[gr + (ch << 3)];
                const int idx = (srow << 6) + ((ch ^ (srow & 7)) << 3);
                *(sh8*)&Qh[idx] = hv; *(sh8*)&Ql[idx] = lv;
            }
        }

        f32x4 oacc[4];
        const f32x4 z4 = {0.f, 0.f, 0.f, 0.f};
        float mrun[4], lrun[4];
        #pragma unroll
        for (int i = 0; i < 4; ++i) { oacc[i] = z4; mrun[i] = -1e30f; lrun[i] = 0.f; }

        for (int t = 0; t <= qt; ++t) {
            const int kvbase = t << 6;
            __syncthreads();
            {   // stage K
                const size_t gr = ((size_t)bh * S_LEN + kvbase + srow) * DK;
                #pragma unroll
                for (int s = 0; s < 2; ++s) {
                    const int ch = sc4 + (s << 2);
                    const sh8 hv = *(const sh8*)&Kh_g[gr + (ch << 3)];
                    const sh8 lv = *(const sh8*)&Kl_g[gr + (ch << 3)];
                    const int idx = (srow << 6) + ((ch ^ (srow & 7)) << 3);
                    *(sh8*)&Kh[idx] = hv; *(sh8*)&Kl[idx] = lv;
                }
            }
            {   // stage V transposed -> [d][kv]
                const size_t gr = ((size_t)bh * S_LEN + kvbase + vr) * DK + vd0;
                const sh8 h0 = *(const sh8*)&Vh_g[gr];
                const sh8 h1 = *(const sh8*)&Vh_g[gr + 8];
                const sh8 l0 = *(const sh8*)&Vl_g[gr];
                const sh8 l1 = *(const sh8*)&Vl_g[gr + 8];
                #pragma unroll
                for (int e = 0; e < 8; ++e) {
                    int d   = vd0 + e;
                    int idx = (d << 6) + ((((vr >> 3)) ^ (d & 7)) << 3) + (vr & 7);
                    Vh[idx] = h0[e]; Vl[idx] = l0[e];
                    d   = vd0 + 8 + e;
                    idx = (d << 6) + ((((vr >> 3)) ^ (d & 7)) << 3) + (vr & 7);
                    Vh[idx] = h1[e]; Vl[idx] = l1[e];
                }
            }
            __syncthreads();

            // ---- QK^T
            f32x4 sacc[4];
            #pragma unroll
            for (int fn = 0; fn < 4; ++fn) sacc[fn] = z4;
            #pragma unroll
            for (int kf = 0; kf < 2; ++kf) {
                const int arow = (w << 4) + l15;
                const int aidx = (arow << 6) + ((((kf << 2) + lg) ^ (arow & 7)) << 3);
                const sh8 qh = *(const sh8*)&Qh[aidx];
                const sh8 ql = *(const sh8*)&Ql[aidx];
                #pragma unroll
                for (int fn = 0; fn < 4; ++fn) {
                    const int brow = (fn << 4) + l15;
                    const int bidx = (brow << 6) + ((((kf << 2) + lg) ^ (brow & 7)) << 3);
                    const sh8 kh = *(const sh8*)&Kh[bidx];
                    const sh8 kl = *(const sh8*)&Kl[bidx];
                    f32x4 c = sacc[fn];
                    c = __builtin_amdgcn_mfma_f32_16x16x32_bf16(qh, kh, c, 0, 0, 0);
                    c = __builtin_amdgcn_mfma_f32_16x16x32_bf16(qh, kl, c, 0, 0, 0);
                    c = __builtin_amdgcn_mfma_f32_16x16x32_bf16(ql, kh, c, 0, 0, 0);
                    sacc[fn] = c;
                }
            }

            // ---- online softmax (row q = (lg<<2)+reg, col kv = 16fn+l15)
            const bool diag = (t == qt);
            #pragma unroll
            for (int reg = 0; reg < 4; ++reg) {
                const int qg = qbase + (w << 4) + (lg << 2) + reg;
                float sv[4];
                float vmax = -1e30f;
                #pragma unroll
                for (int fn = 0; fn < 4; ++fn) {
                    float s = sacc[fn][reg] * 0.125f;
                    if (diag && (kvbase + (fn << 4) + l15 > qg)) s = -1e30f;
                    sv[fn] = s;
                    vmax = fmaxf(vmax, s);
                }
                #pragma unroll
                for (int msk = 1; msk < 16; msk <<= 1)
                    vmax = fmaxf(vmax, __shfl_xor(vmax, msk, 64));
                const float mnew = fmaxf(mrun[reg], vmax);
                const float corr = __expf(mrun[reg] - mnew);
                float rsum = 0.f;
                const int prow = (w << 4) + (lg << 2) + reg;
                #pragma unroll
                for (int fn = 0; fn < 4; ++fn) {
                    const float p = __expf(sv[fn] - mnew);
                    rsum += p;
                    short hs, ls; cvt1(p, hs, ls);
                    const int pcol = (fn << 4) + l15;
                    const int pidx = (prow << 6) + ((((pcol >> 3)) ^ (prow & 7)) << 3) + (pcol & 7);
                    Ph[pidx] = hs; Pl[pidx] = ls;
                }
                #pragma unroll
                for (int msk = 1; msk < 16; msk <<= 1)
                    rsum += __shfl_xor(rsum, msk, 64);
                lrun[reg] = lrun[reg] * corr + rsum;
                mrun[reg] = mnew;
                #pragma unroll
                for (int fn = 0; fn < 4; ++fn) oacc[fn][reg] *= corr;
            }

            // ---- PV (P stripe wave-local, no barrier)
            #pragma unroll
            for (int kf = 0; kf < 2; ++kf) {
                const int arow = (w << 4) + l15;
                const int aidx = (arow << 6) + ((((kf << 2) + lg) ^ (arow & 7)) << 3);
                const sh8 ph = *(const sh8*)&Ph[aidx];
                const sh8 pl = *(const sh8*)&Pl[aidx];
                #pragma unroll
                for (int fn = 0; fn < 4; ++fn) {
                    const int brow = (fn << 4) + l15;
                    const int bidx = (brow << 6) + ((((kf << 2) + lg) ^ (brow & 7)) << 3);
                    const sh8 vh = *(const sh8*)&Vh[bidx];
                    const sh8 vl = *(const sh8*)&Vl[bidx];
                    f32x4 c = oacc[fn];
                    c = __builtin_amdgcn_mfma_f32_16x16x32_bf16(ph, vh, c, 0, 0, 0);
                    c = __builtin_amdgcn_mfma_f32_16x16x32_bf16(ph, vl, c, 0, 0, 0);
                    c = __builtin_amdgcn_mfma_f32_16x16x32_bf16(pl, vh, c, 0, 0, 0);
                    oacc[fn] = c;
                }
            }
        }

        // ---- epilogue: normalize + write hi/lo planes [B][S][D]
        #pragma unroll
        for (int reg = 0; reg < 4; ++reg) {
            const float inv = 1.0f / lrun[reg];
            const int s = qbase + (w << 4) + (lg << 2) + reg;
            const size_t rbase = (size_t)(b * S_LEN + s) * D_DIM + (h << 6);
            #pragma unroll
            for (int fn = 0; fn < 4; ++fn) {
                short hs, ls; cvt1(oacc[fn][reg] * inv, hs, ls);
                ah[rbase + (fn << 4) + l15] = hs;
                al[rbase + (fn << 4) + l15] = ls;
            }
        }
    }
}

// ===========================================================================
// ===== LEGACY PATH (verbatim R8, proven: 504 µs) — used if ws too small ====
// ===========================================================================
template <int MODE>
__global__ __launch_bounds__(256)
void gemm_mfma(const float* __restrict__ A,
               const float* __restrict__ W0,
               const float* __restrict__ W1,
               const float* __restrict__ W2,
               float* __restrict__ O0,
               float* __restrict__ O1,
               float* __restrict__ O2,
               const int* __restrict__ pos)
{
    const float* W; float* Cout; bool rope = false;
    if (MODE == 0) {
        const int z = blockIdx.z;
        W    = (z == 0) ? W0 : (z == 1) ? W1 : W2;
        Cout = (z == 0) ? O0 : (z == 1) ? O1 : O2;
        rope = (z < 2);
    } else { W = W0; Cout = O0; }

    __shared__ short Ah[128 * 64];
    __shared__ short Al[128 * 64];
    __shared__ short Bh[128 * 64];
    __shared__ short Bl[128 * 64];

    const int tid  = threadIdx.x;
    const int bm   = blockIdx.y << 7;
    const int bn   = blockIdx.x << 7;
    const int wid  = tid >> 6;
    const int lane = tid & 63;
    const int wr   = wid >> 1;
    const int wc   = wid & 1;
    const int l15  = lane & 15;
    const int lg   = lane >> 4;

    f32x4 acc[4][4];
    const f32x4 z4 = {0.f, 0.f, 0.f, 0.f};
    #pragma unroll
    for (int i = 0; i < 4; ++i)
        #pragma unroll
        for (int j = 0; j < 4; ++j) acc[i][j] = z4;

    for (int step = 0; step < 16; ++step) {
        const int k0 = step << 6;
        __syncthreads();
        #pragma unroll
        for (int cc = 0; cc < 4; ++cc) {
            const int q   = tid + (cc << 8);
            const int row = q >> 3;
            const int ch  = q & 7;
            const float* src = A + (size_t)(bm + row) * D_DIM + k0 + (ch << 3);
            float4 a0 = *(const float4*)src;
            float4 a1 = *(const float4*)(src + 4);
            sh8 hv, lv; cvt8(a0, a1, hv, lv);
            const int widx = (row << 6) + ((ch ^ (row & 7)) << 3);
            *(sh8*)&Ah[widx] = hv;
            *(sh8*)&Al[widx] = lv;
        }
        #pragma unroll
        for (int cc = 0; cc < 4; ++cc) {
            const int q   = tid + (cc << 8);
            const int row = q >> 3;
            const int ch  = q & 7;
            const float* src = W + (size_t)(bn + row) * D_DIM + k0 + (ch << 3);
            float4 a0 = *(const float4*)src;
            float4 a1 = *(const float4*)(src + 4);
            sh8 hv, lv; cvt8(a0, a1, hv, lv);
            const int widx = (row << 6) + ((ch ^ (row & 7)) << 3);
            *(sh8*)&Bh[widx] = hv;
            *(sh8*)&Bl[widx] = lv;
        }
        __syncthreads();

        #pragma unroll
        for (int kf = 0; kf < 2; ++kf) {
            sh8 fah[4], fal[4], fbh[4], fbl[4];
            #pragma unroll
            for (int fm = 0; fm < 4; ++fm) {
                const int row = (wr << 6) + (fm << 4) + l15;
                const int idx = (row << 6) + ((((kf << 2) + lg) ^ (row & 7)) << 3);
                fah[fm] = *(const sh8*)&Ah[idx];
                fal[fm] = *(const sh8*)&Al[idx];
            }
            #pragma unroll
            for (int fn = 0; fn < 4; ++fn) {
                const int row = (wc << 6) + (fn << 4) + l15;
                const int idx = (row << 6) + ((((kf << 2) + lg) ^ (row & 7)) << 3);
                fbh[fn] = *(const sh8*)&Bh[idx];
                fbl[fn] = *(const sh8*)&Bl[idx];
            }
            #pragma unroll
            for (int fm = 0; fm < 4; ++fm)
                #pragma unroll
                for (int fn = 0; fn < 4; ++fn) {
                    f32x4 c = acc[fm][fn];
                    c = __builtin_amdgcn_mfma_f32_16x16x32_bf16(fah[fm], fbh[fn], c, 0, 0, 0);
                    c = __builtin_amdgcn_mfma_f32_16x16x32_bf16(fah[fm], fbl[fn], c, 0, 0, 0);
                    c = __builtin_amdgcn_mfma_f32_16x16x32_bf16(fal[fm], fbh[fn], c, 0, 0, 0);
                    acc[fm][fn] = c;
                }
        }
    }

    #pragma unroll
    for (int fn = 0; fn < 4; ++fn) {
        const int colg = bn + (wc << 6) + (fn << 4) + l15;
        float freq = 0.f;
        if (MODE == 0 && rope) {
            const int f = (colg & 63) >> 1;
            freq = powf(10000.0f, -(float)(2 * f) * (1.0f / 64.0f));
        }
        #pragma unroll
        for (int fm = 0; fm < 4; ++fm) {
            #pragma unroll
            for (int r = 0; r < 4; ++r) {
                const int m = bm + (wr << 6) + (fm << 4) + (lg << 2) + r;
                float own = acc[fm][fn][r];
                if (MODE == 0) {
                    const int b = m >> 11, s = m & (S_LEN - 1);
                    const int h = colg >> 6, d = colg & 63;
                    float y = own;
                    float other = __shfl_xor(own, 1, 64);
                    if (rope) {
                        const float ang = (float)pos[s] * freq;
                        float sn, cs; sincosf(ang, &sn, &cs);
                        y = (d & 1) ? fmaf(other, sn, own * cs)
                                    : fmaf(-other, sn, own * cs);
                    }
                    Cout[((size_t)(b * H_NUM + h) * S_LEN + s) * DK + d] = y;
                } else {
                    Cout[(size_t)m * D_DIM + colg] = own;
                }
            }
        }
    }
}

__global__ __launch_bounds__(256)
void flash_kernel(const float* __restrict__ Q,
                  const float* __restrict__ Kin,
                  const float* __restrict__ V,
                  float* __restrict__ Oout)
{
    __shared__ short Qh[4096], Ql[4096];
    __shared__ short Kh[4096], Kl[4096];
    __shared__ short Vh[4096], Vl[4096];
    __shared__ short Ph[4096], Pl[4096];

    const int pair = blockIdx.x;
    const int bh   = blockIdx.y;
    const int tid  = threadIdx.x;
    const int lane = tid & 63;
    const int w    = tid >> 6;
    const int l15  = lane & 15;
    const int lg   = lane >> 4;

    const float* Kp = Kin + (size_t)bh * S_LEN * DK;
    const float* Vp = V   + (size_t)bh * S_LEN * DK;
    const int b = bh >> 4, h = bh & 15;

    const int srow = tid >> 2;
    const int sc4  = tid & 3;
    const int vr   = tid & 63;
    const int vd0  = (tid >> 6) << 4;

    for (int half = 0; half < 2; ++half) {
        const int qt    = half ? (31 - pair) : pair;
        const int qbase = qt << 6;

        __syncthreads();
        {
            const float* qsrc = Q + ((size_t)bh * S_LEN + qbase + srow) * DK;
            #pragma unroll
            for (int s = 0; s < 2; ++s) {
                const int ch = sc4 + (s << 2);
                const float4 a0 = *(const float4*)(qsrc + (ch << 3));
                const float4 a1 = *(const float4*)(qsrc + (ch << 3) + 4);
                sh8 hv, lv; cvt8(a0, a1, hv, lv);
                const int idx = (srow << 6) + ((ch ^ (srow & 7)) << 3);
                *(sh8*)&Qh[idx] = hv; *(sh8*)&Ql[idx] = lv;
            }
        }

        f32x4 oacc[4];
        const f32x4 z4 = {0.f, 0.f, 0.f, 0.f};
        float mrun[4], lrun[4];
        #pragma unroll
        for (int i = 0; i < 4; ++i) { oacc[i] = z4; mrun[i] = -1e30f; lrun[i] = 0.f; }

        for (int t = 0; t <= qt; ++t) {
            const int kvbase = t << 6;
            __syncthreads();
            {
                const float* ksrc = Kp + (size_t)(kvbase + srow) * DK;
                #pragma unroll
                for (int s = 0; s < 2; ++s) {
                    const int ch = sc4 + (s << 2);
                    const float4 a0 = *(const float4*)(ksrc + (ch << 3));
                    const float4 a1 = *(const float4*)(ksrc + (ch << 3) + 4);
                    sh8 hv, lv; cvt8(a0, a1, hv, lv);
                    const int idx = (srow << 6) + ((ch ^ (srow & 7)) << 3);
                    *(sh8*)&Kh[idx] = hv; *(sh8*)&Kl[idx] = lv;
                }
            }
            {
                const float* vsrc = Vp + (size_t)(kvbase + vr) * DK + vd0;
                const float4 v0 = *(const float4*)(vsrc);
                const float4 v1 = *(const float4*)(vsrc + 4);
                const float4 v2 = *(const float4*)(vsrc + 8);
                const float4 v3 = *(const float4*)(vsrc + 12);
                sh8 h0, l0, h1, l1;
                cvt8(v0, v1, h0, l0);
                cvt8(v2, v3, h1, l1);
                #pragma unroll
                for (int e = 0; e < 8; ++e) {
                    int d   = vd0 + e;
                    int idx = (d << 6) + ((((vr >> 3)) ^ (d & 7)) << 3) + (vr & 7);
                    Vh[idx] = h0[e]; Vl[idx] = l0[e];
                    d   = vd0 + 8 + e;
                    idx = (d << 6) + ((((vr >> 3)) ^ (d & 7)) << 3) + (vr & 7);
                    Vh[idx] = h1[e]; Vl[idx] = l1[e];
                }
            }
            __syncthreads();

            f32x4 sacc[4];
            #pragma unroll
            for (int fn = 0; fn < 4; ++fn) sacc[fn] = z4;
            #pragma unroll
            for (int kf = 0; kf < 2; ++kf) {
                const int arow = (w << 4) + l15;
                const int aidx = (arow << 6) + ((((kf << 2) + lg) ^ (arow & 7)) << 3);
                const sh8 qh = *(const sh8*)&Qh[aidx];
                const sh8 ql = *(const sh8*)&Ql[aidx];
                #pragma unroll
                for (int fn = 0; fn < 4; ++fn) {
                    const int brow = (fn << 4) + l15;
                    const int bidx = (brow << 6) + ((((kf << 2) + lg) ^ (brow & 7)) << 3);
                    const sh8 kh = *(const sh8*)&Kh[bidx];
                    const sh8 kl = *(const sh8*)&Kl[bidx];
                    f32x4 c = sacc[fn];
                    c = __builtin_amdgcn_mfma_f32_16x16x32_bf16(qh, kh, c, 0, 0, 0);
                    c = __builtin_amdgcn_mfma_f32_16x16x32_bf16(qh, kl, c, 0, 0, 0);
                    c = __builtin_amdgcn_mfma_f32_16x16x32_bf16(ql, kh, c, 0, 0, 0);
                    sacc[fn] = c;
                }
            }

            const bool diag = (t == qt);
            #pragma unroll
            for (int reg = 0; reg < 4; ++reg) {
                const int qg = qbase + (w << 4) + (lg << 2) + reg;
                float sv[4];
                float vmax = -1e30f;
                #pragma unroll
                for (int fn = 0; fn < 4; ++fn) {
                    float s = sacc[fn][reg] * 0.125f;
                    if (diag && (kvbase + (fn << 4) + l15 > qg)) s = -1e30f;
                    sv[fn] = s;
                    vmax = fmaxf(vmax, s);
                }
                #pragma unroll
                for (int msk = 1; msk < 16; msk <<= 1)
                    vmax = fmaxf(vmax, __shfl_xor(vmax, msk, 64));
                const float mnew = fmaxf(mrun[reg], vmax);
                const float corr = __expf(mrun[reg] - mnew);
                float rsum = 0.f;
                const int prow = (w << 4) + (lg << 2) + reg;
                #pragma unroll
                for (int fn = 0; fn < 4; ++fn) {
                    const float p = __expf(sv[fn] - mnew);
                    rsum += p;
                    short hs, ls; cvt1(p, hs, ls);
                    const int pcol = (fn << 4) + l15;
                    const int pidx = (prow << 6) + ((((pcol >> 3)) ^ (prow & 7)) << 3) + (pcol & 7);
                    Ph[pidx] = hs; Pl[pidx] = ls;
                }
                #pragma unroll
                for (int msk = 1; msk < 16; msk <<= 1)
                    rsum += __shfl_xor(rsum, msk, 64);
                lrun[reg] = lrun[reg] * corr + rsum;
                mrun[reg] = mnew;
                #pragma unroll
                for (int fn = 0; fn < 4; ++fn) oacc[fn][reg] *= corr;
            }

            #pragma unroll
            for (int kf = 0; kf < 2; ++kf) {
                const int arow = (w << 4) + l15;
                const int aidx = (arow << 6) + ((((kf << 2) + lg) ^ (arow & 7)) << 3);
                const sh8 ph = *(const sh8*)&Ph[aidx];
                const sh8 pl = *(const sh8*)&Pl[aidx];
                #pragma unroll
                for (int fn = 0; fn < 4; ++fn) {
                    const int brow = (fn << 4) + l15;
                    const int bidx = (brow << 6) + ((((kf << 2) + lg) ^ (brow & 7)) << 3);
                    const sh8 vh = *(const sh8*)&Vh[bidx];
                    const sh8 vl = *(const sh8*)&Vl[bidx];
                    f32x4 c = oacc[fn];
                    c = __builtin_amdgcn_mfma_f32_16x16x32_bf16(ph, vh, c, 0, 0, 0);
                    c = __builtin_amdgcn_mfma_f32_16x16x32_bf16(ph, vl, c, 0, 0, 0);
                    c = __builtin_amdgcn_mfma_f32_16x16x32_bf16(pl, vh, c, 0, 0, 0);
                    oacc[fn] = c;
                }
            }
        }

        #pragma unroll
        for (int reg = 0; reg < 4; ++reg) {
            const float inv = 1.0f / lrun[reg];
            const int s = qbase + (w << 4) + (lg << 2) + reg;
            float* orow = Oout + (size_t)(b * S_LEN + s) * D_DIM + (h << 6);
            #pragma unroll
            for (int fn = 0; fn < 4; ++fn)
                orow[(fn << 4) + l15] = oacc[fn][reg] * inv;
        }
    }
}

// ---------------------------------------------------------------------------
extern "C" void kernel_launch(void* const* d_in, const int* in_sizes, int n_in,
                              void* d_out, int out_size, void* d_ws, size_t ws_size,
                              hipStream_t stream)
{
    const float* x  = (const float*)d_in[0];
    const int*  pos = (const int*) d_in[1];
    const float* Wq = (const float*)d_in[2];
    const float* Wk = (const float*)d_in[3];
    const float* Wv = (const float*)d_in[4];
    const float* Wo = (const float*)d_in[5];
    float* out = (float*)d_out;

    // planes layout (shorts): xh(4M) xl(4M) w8(8M) qkv(24M) ; ah/al alias xh/xl
    const size_t need = (size_t)(4 + 4 + 8 + 24) * 1024 * 1024 * 2;  // 80 MB

    if (ws_size >= need) {
        short* xh  = (short*)d_ws;
        short* xl  = xh + PLANE;
        short* w8  = xl + PLANE;
        short* qkv = w8 + 8u * WPLANE;
        short* ah  = xh;           // x planes dead after QKV gemm
        short* al  = xl;

        split_kernel<<<dim3(512, 5), dim3(256), 0, stream>>>(
            x, Wq, Wk, Wv, Wo, xh, xl, w8);

        dim3 gq(D_DIM / 128, M_ROWS / 128, 3);
        gemm2<0><<<gq, dim3(256), 0, stream>>>(xh, xl, w8, qkv, nullptr, pos);

        dim3 gf(16, B_NUM * H_NUM);
        flash2<<<gf, dim3(256), 0, stream>>>(qkv, ah, al);

        dim3 go(D_DIM / 128, M_ROWS / 128, 1);
        gemm2<1><<<go, dim3(256), 0, stream>>>(ah, al, w8, nullptr, out, nullptr);
    } else {
        // legacy R8 path (proven 504 µs)
        const size_t elems = (size_t)B_NUM * S_LEN * D_DIM;
        float* qws = (float*)d_ws;
        float* kws = qws + elems;
        float* vws = kws + elems;
        float* aws = vws + elems;

        dim3 gq(D_DIM / 128, M_ROWS / 128, 3);
        gemm_mfma<0><<<gq, dim3(256), 0, stream>>>(x, Wq, Wk, Wv, qws, kws, vws, pos);

        dim3 gf(16, B_NUM * H_NUM);
        flash_kernel<<<gf, dim3(256), 0, stream>>>(qws, kws, vws, aws);

        dim3 go(D_DIM / 128, M_ROWS / 128, 1);
        gemm_mfma<1><<<go, dim3(256), 0, stream>>>(aws, Wo, nullptr, nullptr,
                                                   out, nullptr, nullptr, nullptr);
    }
}

// Round 10
// 384.018 us; speedup vs baseline: 2.8041x; 1.0432x over previous
//
#include <hip/hip_runtime.h>
#include <math.h>

#define S_LEN 2048
#define D_DIM 1024
#define H_NUM 16
#define DK    64
#define B_NUM 2
#define M_ROWS (B_NUM * S_LEN)   // 4096

typedef __attribute__((ext_vector_type(8))) short sh8;   // 8 bf16 (4 VGPRs)
typedef __attribute__((ext_vector_type(4))) float f32x4; // MFMA C/D

// fp32 -> bf16 hi (RNE) + bf16 lo (residual, RNE). a - float(hi) is exact.
__device__ inline void cvt8(const float4 a, const float4 b, sh8& hi, sh8& lo)
{
    float in[8] = {a.x, a.y, a.z, a.w, b.x, b.y, b.z, b.w};
    #pragma unroll
    for (int i = 0; i < 8; ++i) {
        unsigned u  = __float_as_uint(in[i]);
        unsigned hr = (u + 0x7FFFu + ((u >> 16) & 1u)) >> 16;
        float    hf = __uint_as_float(hr << 16);
        hi[i] = (short)hr;
        float    r  = in[i] - hf;
        unsigned ur = __float_as_uint(r);
        unsigned lr = (ur + 0x7FFFu + ((ur >> 16) & 1u)) >> 16;
        lo[i] = (short)lr;
    }
}

__device__ inline void cvt1(float x, short& h, short& l)
{
    unsigned u  = __float_as_uint(x);
    unsigned hr = (u + 0x7FFFu + ((u >> 16) & 1u)) >> 16;
    h = (short)hr;
    float    r  = x - __uint_as_float(hr << 16);
    unsigned ur = __float_as_uint(r);
    l = (short)((ur + 0x7FFFu + ((ur >> 16) & 1u)) >> 16);
}

// async global->LDS, 16B per lane; LDS base wave-uniform, global addr per-lane
__device__ __forceinline__ void glds16(const void* g, void* l)
{
    __builtin_amdgcn_global_load_lds(
        (const __attribute__((address_space(1))) void*)g,
        (__attribute__((address_space(3))) void*)l, 16, 0, 0);
}

#define PLANE (4u * 1024u * 1024u)   // 4M elements (one [4096][1024] plane)
#define WPLANE (1024u * 1024u)

// ===========================================================================
// split_kernel: x + 4 weights -> bf16 hi/lo planes (one-time pass).
// VERIFIED R9. Unchanged.
// ===========================================================================
__global__ __launch_bounds__(256)
void split_kernel(const float* __restrict__ x,
                  const float* __restrict__ wq, const float* __restrict__ wk,
                  const float* __restrict__ wv, const float* __restrict__ wo,
                  short* __restrict__ xh, short* __restrict__ xl,
                  short* __restrict__ w8)
{
    const int t = blockIdx.x * 256 + threadIdx.x;   // 0..131071
    const int y = blockIdx.y;
    if (y == 0) {
        #pragma unroll
        for (int i = 0; i < 4; ++i) {
            const size_t u = (size_t)t + (size_t)i * 131072u;
            const float4 a0 = *(const float4*)(x + u * 8);
            const float4 a1 = *(const float4*)(x + u * 8 + 4);
            sh8 hv, lv; cvt8(a0, a1, hv, lv);
            *(sh8*)&xh[u * 8] = hv;
            *(sh8*)&xl[u * 8] = lv;
        }
    } else {
        const float* src = (y == 1) ? wq : (y == 2) ? wk : (y == 3) ? wv : wo;
        short* dh = w8 + (size_t)(y - 1) * 2 * WPLANE;
        short* dl = dh + WPLANE;
        const size_t u = (size_t)t;
        const float4 a0 = *(const float4*)(src + u * 8);
        const float4 a1 = *(const float4*)(src + u * 8 + 4);
        sh8 hv, lv; cvt8(a0, a1, hv, lv);
        *(sh8*)&dh[u * 8] = hv;
        *(sh8*)&dl[u * 8] = lv;
    }
}

// ===========================================================================
// gemm2: MFMA GEMM on pre-split planes. THIS ROUND: staging via
// global_load_lds width=16 — linear LDS dest (wave-uniform base + lane*16),
// chunk swizzle c^=(row&7) applied to the per-lane GLOBAL source address,
// frag-read keeps the same XOR (rule #21: same involution both sides).
// Per wave per K-step: 16 glds16 calls (4 slots x {Ah,Al,Bh,Bl}); swizzle
// offsets precomputed outside the K-loop.
// ===========================================================================
template <int MODE>
__global__ __launch_bounds__(256)
void gemm2(const short* __restrict__ Agh, const short* __restrict__ Agl,
           const short* __restrict__ w8,
           short* __restrict__ qkv,      // MODE 0 out planes base
           float* __restrict__ outf,     // MODE 1 out
           const int* __restrict__ pos)
{
    const int z = (MODE == 0) ? blockIdx.z : 3;
    const short* Wh_g = w8 + (size_t)z * 2 * WPLANE;
    const short* Wl_g = Wh_g + WPLANE;
    const bool rope = (MODE == 0) && (z < 2);
    short* Oh = (MODE == 0) ? qkv + (size_t)z * 2 * PLANE : nullptr;
    short* Ol = (MODE == 0) ? Oh + PLANE : nullptr;

    __shared__ short Ah[128 * 64];
    __shared__ short Al[128 * 64];
    __shared__ short Bh[128 * 64];
    __shared__ short Bl[128 * 64];

    const int tid  = threadIdx.x;
    const int bm   = blockIdx.y << 7;
    const int bn   = blockIdx.x << 7;
    const int wid  = tid >> 6;
    const int lane = tid & 63;
    const int wr   = wid >> 1;
    const int wc   = wid & 1;
    const int l15  = lane & 15;
    const int lg   = lane >> 4;

    // staging slots: wave wid, slot i, lane L -> row = wid*32 + i*8 + L/8,
    // chunk c = L%8; global src offset uses swizzled chunk c^(row&7).
    int srow4[4], soff4[4];
    #pragma unroll
    for (int i = 0; i < 4; ++i) {
        const int r = (wid << 5) + (i << 3) + (lane >> 3);
        srow4[i] = r;
        soff4[i] = ((lane & 7) ^ (r & 7)) << 3;   // shorts
    }

    f32x4 acc[4][4];
    const f32x4 z4 = {0.f, 0.f, 0.f, 0.f};
    #pragma unroll
    for (int i = 0; i < 4; ++i)
        #pragma unroll
        for (int j = 0; j < 4; ++j) acc[i][j] = z4;

    for (int step = 0; step < 16; ++step) {
        const int k0 = step << 6;
        __syncthreads();
        #pragma unroll
        for (int i = 0; i < 4; ++i) {
            const int r = srow4[i];
            const size_t ga = (size_t)(bm + r) * D_DIM + k0 + soff4[i];
            const size_t gb = (size_t)(bn + r) * D_DIM + k0 + soff4[i];
            const int ld = ((wid << 2) + i) << 9;   // *512 shorts = 1 KB
            glds16(&Agh[ga],  &Ah[ld]);
            glds16(&Agl[ga],  &Al[ld]);
            glds16(&Wh_g[gb], &Bh[ld]);
            glds16(&Wl_g[gb], &Bl[ld]);
        }
        __syncthreads();   // compiler drains vmcnt(0) before barrier

        #pragma unroll
        for (int kf = 0; kf < 2; ++kf) {
            sh8 fah[4], fal[4], fbh[4], fbl[4];
            #pragma unroll
            for (int fm = 0; fm < 4; ++fm) {
                const int row = (wr << 6) + (fm << 4) + l15;
                const int idx = (row << 6) + ((((kf << 2) + lg) ^ (row & 7)) << 3);
                fah[fm] = *(const sh8*)&Ah[idx];
                fal[fm] = *(const sh8*)&Al[idx];
            }
            #pragma unroll
            for (int fn = 0; fn < 4; ++fn) {
                const int row = (wc << 6) + (fn << 4) + l15;
                const int idx = (row << 6) + ((((kf << 2) + lg) ^ (row & 7)) << 3);
                fbh[fn] = *(const sh8*)&Bh[idx];
                fbl[fn] = *(const sh8*)&Bl[idx];
            }
            #pragma unroll
            for (int fm = 0; fm < 4; ++fm)
                #pragma unroll
                for (int fn = 0; fn < 4; ++fn) {
                    f32x4 c = acc[fm][fn];
                    c = __builtin_amdgcn_mfma_f32_16x16x32_bf16(fah[fm], fbh[fn], c, 0, 0, 0);
                    c = __builtin_amdgcn_mfma_f32_16x16x32_bf16(fah[fm], fbl[fn], c, 0, 0, 0);
                    c = __builtin_amdgcn_mfma_f32_16x16x32_bf16(fal[fm], fbh[fn], c, 0, 0, 0);
                    acc[fm][fn] = c;
                }
        }
    }

    // epilogue: C/D layout col = lane&15, row = (lane>>4)*4 + reg  [m89]
    #pragma unroll
    for (int fn = 0; fn < 4; ++fn) {
        const int colg = bn + (wc << 6) + (fn << 4) + l15;
        float freq = 0.f;
        if (rope) {
            const int f = (colg & 63) >> 1;
            freq = powf(10000.0f, -(float)(2 * f) * (1.0f / 64.0f));
        }
        #pragma unroll
        for (int fm = 0; fm < 4; ++fm) {
            #pragma unroll
            for (int r = 0; r < 4; ++r) {
                const int m = bm + (wr << 6) + (fm << 4) + (lg << 2) + r;
                float own = acc[fm][fn][r];
                if (MODE == 0) {
                    const int b = m >> 11, s = m & (S_LEN - 1);
                    const int h = colg >> 6, d = colg & 63;
                    float y = own;
                    float other = __shfl_xor(own, 1, 64);
                    if (rope) {
                        const float ang = (float)pos[s] * freq;
                        float sn, cs; sincosf(ang, &sn, &cs);
                        y = (d & 1) ? fmaf(other, sn, own * cs)
                                    : fmaf(-other, sn, own * cs);
                    }
                    short hs, ls; cvt1(y, hs, ls);
                    const size_t addr = ((size_t)(b * H_NUM + h) * S_LEN + s) * DK + d;
                    Oh[addr] = hs; Ol[addr] = ls;
                } else {
                    outf[(size_t)m * D_DIM + colg] = own;
                }
            }
        }
    }
}

// ===========================================================================
// flash2: MFMA flash attention on hi/lo planes. VERIFIED R9. Unchanged.
// ===========================================================================
__global__ __launch_bounds__(256)
void flash2(const short* __restrict__ qkv,
            short* __restrict__ ah, short* __restrict__ al)
{
    const short* Qh_g = qkv;
    const short* Ql_g = qkv + PLANE;
    const short* Kh_g = qkv + 2u * PLANE;
    const short* Kl_g = qkv + 3u * PLANE;
    const short* Vh_g = qkv + 4u * PLANE;
    const short* Vl_g = qkv + 5u * PLANE;

    __shared__ short Qh[4096], Ql[4096];
    __shared__ short Kh[4096], Kl[4096];
    __shared__ short Vh[4096], Vl[4096];   // transposed [d][kv]
    __shared__ short Ph[4096], Pl[4096];   // [q][kv]

    const int pair = blockIdx.x;   // 0..15
    const int bh   = blockIdx.y;   // 0..31
    const int tid  = threadIdx.x;
    const int lane = tid & 63;
    const int w    = tid >> 6;
    const int l15  = lane & 15;
    const int lg   = lane >> 4;

    const int b = bh >> 4, h = bh & 15;

    const int srow = tid >> 2;          // staging row 0..63
    const int sc4  = tid & 3;
    const int vr   = tid & 63;          // V staging: kv row
    const int vd0  = (tid >> 6) << 4;   // V staging: d block

    for (int half = 0; half < 2; ++half) {
        const int qt    = half ? (31 - pair) : pair;
        const int qbase = qt << 6;

        __syncthreads();   // protect Qh/Ql from prior half's readers
        {   // stage Q
            const size_t gr = ((size_t)bh * S_LEN + qbase + srow) * DK;
            #pragma unroll
            for (int s = 0; s < 2; ++s) {
                const int ch = sc4 + (s << 2);
                const sh8 hv = *(const sh8*)&Qh_g[gr + (ch << 3)];
                const sh8 lv = *(const sh8*)&Ql_g[gr + (ch << 3)];
                const int idx = (srow << 6) + ((ch ^ (srow & 7)) << 3);
                *(sh8*)&Qh[idx] = hv; *(sh8*)&Ql[idx] = lv;
            }
        }

        f32x4 oacc[4];
        const f32x4 z4 = {0.f, 0.f, 0.f, 0.f};
        float mrun[4], lrun[4];
        #pragma unroll
        for (int i = 0; i < 4; ++i) { oacc[i] = z4; mrun[i] = -1e30f; lrun[i] = 0.f; }

        for (int t = 0; t <= qt; ++t) {
            const int kvbase = t << 6;
            __syncthreads();
            {   // stage K
                const size_t gr = ((size_t)bh * S_LEN + kvbase + srow) * DK;
                #pragma unroll
                for (int s = 0; s < 2; ++s) {
                    const int ch = sc4 + (s << 2);
                    const sh8 hv = *(const sh8*)&Kh_g[gr + (ch << 3)];
                    const sh8 lv = *(const sh8*)&Kl_g[gr + (ch << 3)];
                    const int idx = (srow << 6) + ((ch ^ (srow & 7)) << 3);
                    *(sh8*)&Kh[idx] = hv; *(sh8*)&Kl[idx] = lv;
                }
            }
            {   // stage V transposed -> [d][kv]
                const size_t gr = ((size_t)bh * S_LEN + kvbase + vr) * DK + vd0;
                const sh8 h0 = *(const sh8*)&Vh_g[gr];
                const sh8 h1 = *(const sh8*)&Vh_g[gr + 8];
                const sh8 l0 = *(const sh8*)&Vl_g[gr];
                const sh8 l1 = *(const sh8*)&Vl_g[gr + 8];
                #pragma unroll
                for (int e = 0; e < 8; ++e) {
                    int d   = vd0 + e;
                    int idx = (d << 6) + ((((vr >> 3)) ^ (d & 7)) << 3) + (vr & 7);
                    Vh[idx] = h0[e]; Vl[idx] = l0[e];
                    d   = vd0 + 8 + e;
                    idx = (d << 6) + ((((vr >> 3)) ^ (d & 7)) << 3) + (vr & 7);
                    Vh[idx] = h1[e]; Vl[idx] = l1[e];
                }
            }
            __syncthreads();

            // ---- QK^T
            f32x4 sacc[4];
            #pragma unroll
            for (int fn = 0; fn < 4; ++fn) sacc[fn] = z4;
            #pragma unroll
            for (int kf = 0; kf < 2; ++kf) {
                const int arow = (w << 4) + l15;
                const int aidx = (arow << 6) + ((((kf << 2) + lg) ^ (arow & 7)) << 3);
                const sh8 qh = *(const sh8*)&Qh[aidx];
                const sh8 ql = *(const sh8*)&Ql[aidx];
                #pragma unroll
                for (int fn = 0; fn < 4; ++fn) {
                    const int brow = (fn << 4) + l15;
                    const int bidx = (brow << 6) + ((((kf << 2) + lg) ^ (brow & 7)) << 3);
                    const sh8 kh = *(const sh8*)&Kh[bidx];
                    const sh8 kl = *(const sh8*)&Kl[bidx];
                    f32x4 c = sacc[fn];
                    c = __builtin_amdgcn_mfma_f32_16x16x32_bf16(qh, kh, c, 0, 0, 0);
                    c = __builtin_amdgcn_mfma_f32_16x16x32_bf16(qh, kl, c, 0, 0, 0);
                    c = __builtin_amdgcn_mfma_f32_16x16x32_bf16(ql, kh, c, 0, 0, 0);
                    sacc[fn] = c;
                }
            }

            // ---- online softmax (row q = (lg<<2)+reg, col kv = 16fn+l15)
            const bool diag = (t == qt);
            #pragma unroll
            for (int reg = 0; reg < 4; ++reg) {
                const int qg = qbase + (w << 4) + (lg << 2) + reg;
                float sv[4];
                float vmax = -1e30f;
                #pragma unroll
                for (int fn = 0; fn < 4; ++fn) {
                    float s = sacc[fn][reg] * 0.125f;
                    if (diag && (kvbase + (fn << 4) + l15 > qg)) s = -1e30f;
                    sv[fn] = s;
                    vmax = fmaxf(vmax, s);
                }
                #pragma unroll
                for (int msk = 1; msk < 16; msk <<= 1)
                    vmax = fmaxf(vmax, __shfl_xor(vmax, msk, 64));
                const float mnew = fmaxf(mrun[reg], vmax);
                const float corr = __expf(mrun[reg] - mnew);
                float rsum = 0.f;
                const int prow = (w << 4) + (lg << 2) + reg;
                #pragma unroll
                for (int fn = 0; fn < 4; ++fn) {
                    const float p = __expf(sv[fn] - mnew);
                    rsum += p;
                    short hs, ls; cvt1(p, hs, ls);
                    const int pcol = (fn << 4) + l15;
                    const int pidx = (prow << 6) + ((((pcol >> 3)) ^ (prow & 7)) << 3) + (pcol & 7);
                    Ph[pidx] = hs; Pl[pidx] = ls;
                }
                #pragma unroll
                for (int msk = 1; msk < 16; msk <<= 1)
                    rsum += __shfl_xor(rsum, msk, 64);
                lrun[reg] = lrun[reg] * corr + rsum;
                mrun[reg] = mnew;
                #pragma unroll
                for (int fn = 0; fn < 4; ++fn) oacc[fn][reg] *= corr;
            }

            // ---- PV (P stripe wave-local, no barrier)
            #pragma unroll
            for (int kf = 0; kf < 2; ++kf) {
                const int arow = (w << 4) + l15;
                const int aidx = (arow << 6) + ((((kf << 2) + lg) ^ (arow & 7)) << 3);
                const sh8 ph = *(const sh8*)&Ph[aidx];
                const sh8 pl = *(const sh8*)&Pl[aidx];
                #pragma unroll
                for (int fn = 0; fn < 4; ++fn) {
                    const int brow = (fn << 4) + l15;
                    const int bidx = (brow << 6) + ((((kf << 2) + lg) ^ (brow & 7)) << 3);
                    const sh8 vh = *(const sh8*)&Vh[bidx];
                    const sh8 vl = *(const sh8*)&Vl[bidx];
                    f32x4 c = oacc[fn];
                    c = __builtin_amdgcn_mfma_f32_16x16x32_bf16(ph, vh, c, 0, 0, 0);
                    c = __builtin_amdgcn_mfma_f32_16x16x32_bf16(ph, vl, c, 0, 0, 0);
                    c = __builtin_amdgcn_mfma_f32_16x16x32_bf16(pl, vh, c, 0, 0, 0);
                    oacc[fn] = c;
                }
            }
        }

        // ---- epilogue: normalize + write hi/lo planes [B][S][D]
        #pragma unroll
        for (int reg = 0; reg < 4; ++reg) {
            const float inv = 1.0f / lrun[reg];
            const int s = qbase + (w << 4) + (lg << 2) + reg;
            const size_t rbase = (size_t)(b * S_LEN + s) * D_DIM + (h << 6);
            #pragma unroll
            for (int fn = 0; fn < 4; ++fn) {
                short hs, ls; cvt1(oacc[fn][reg] * inv, hs, ls);
                ah[rbase + (fn << 4) + l15] = hs;
                al[rbase + (fn << 4) + l15] = ls;
            }
        }
    }
}

// ---------------------------------------------------------------------------
extern "C" void kernel_launch(void* const* d_in, const int* in_sizes, int n_in,
                              void* d_out, int out_size, void* d_ws, size_t ws_size,
                              hipStream_t stream)
{
    const float* x  = (const float*)d_in[0];
    const int*  pos = (const int*) d_in[1];
    const float* Wq = (const float*)d_in[2];
    const float* Wk = (const float*)d_in[3];
    const float* Wv = (const float*)d_in[4];
    const float* Wo = (const float*)d_in[5];
    float* out = (float*)d_out;

    // planes layout (shorts): xh(4M) xl(4M) w8(8M) qkv(24M); ah/al alias xh/xl
    // ws_size >= 80 MB proven R9 (planes path executed).
    short* xh  = (short*)d_ws;
    short* xl  = xh + PLANE;
    short* w8  = xl + PLANE;
    short* qkv = w8 + 8u * WPLANE;
    short* ah  = xh;           // x planes dead after QKV gemm
    short* al  = xl;

    split_kernel<<<dim3(512, 5), dim3(256), 0, stream>>>(
        x, Wq, Wk, Wv, Wo, xh, xl, w8);

    dim3 gq(D_DIM / 128, M_ROWS / 128, 3);
    gemm2<0><<<gq, dim3(256), 0, stream>>>(xh, xl, w8, qkv, nullptr, pos);

    dim3 gf(16, B_NUM * H_NUM);
    flash2<<<gf, dim3(256), 0, stream>>>(qkv, ah, al);

    dim3 go(D_DIM / 128, M_ROWS / 128, 1);
    gemm2<1><<<go, dim3(256), 0, stream>>>(ah, al, w8, nullptr, out, nullptr);
}